// Round 3
// baseline (599.283 us; speedup 1.0000x reference)
//
#include <hip/hip_runtime.h>

#define B_ 16
#define C_ 64
#define N_ 307
#define T_ 288
#define R_ 10
#define M_ (C_ * N_)  // 19648 = 307*64

typedef __attribute__((ext_vector_type(8))) short bf16x8;
typedef __attribute__((ext_vector_type(4))) float f32x4;

__device__ __forceinline__ unsigned short f2bf(float f) {
    unsigned int u = __float_as_uint(f);
    unsigned int r = (u + 0x7fffu + ((u >> 16) & 1u)) >> 16;  // RNE
    return (unsigned short)r;
}
__device__ __forceinline__ unsigned int pack2(float a, float b) {
    return (unsigned int)f2bf(a) | ((unsigned int)f2bf(b) << 16);
}
__device__ __forceinline__ uint4 pack8(float4 a, float4 b) {
    uint4 w;
    w.x = pack2(a.x, a.y); w.y = pack2(a.z, a.w);
    w.z = pack2(b.x, b.y); w.w = pack2(b.z, b.w);
    return w;
}

// ---------------------------------------------------------------------------
// Kernel 1: Kt[b,n,t] = sum_i alpha[i]*x[b,i,n,t]  (note: [n][t] layout so
// writes are coalesced), optionally xbf = bf16(x). Thread per (b,n,t8):
// reads 32B/lane/channel contiguous, writes 16B xbf + 32B Kt contiguous.
// ---------------------------------------------------------------------------
template <int WRITE_BF>
__global__ __launch_bounds__(256) void k_reduce(const float* __restrict__ x,
                                                const float* __restrict__ alpha,
                                                float* __restrict__ Kt,
                                                unsigned short* __restrict__ xbf) {
    __shared__ float a_s[C_];
    if (threadIdx.x < C_) a_s[threadIdx.x] = alpha[threadIdx.x];
    __syncthreads();
    const int T8 = T_ / 8;  // 36
    int idx = blockIdx.x * blockDim.x + threadIdx.x;
    const int total = B_ * N_ * T8;
    if (idx >= total) return;
    int t8 = idx % T8;
    int n = (idx / T8) % N_;
    int b = idx / (N_ * T8);
    const size_t chs = (size_t)N_ * T_;
    size_t base = ((size_t)(b * C_) * N_ + n) * T_ + t8 * 8;
    float4 s0 = {0.f, 0.f, 0.f, 0.f}, s1 = {0.f, 0.f, 0.f, 0.f};
#pragma unroll 4
    for (int i = 0; i < C_; ++i) {
        float4 v0 = *(const float4*)(x + base + (size_t)i * chs);
        float4 v1 = *(const float4*)(x + base + (size_t)i * chs + 4);
        float a = a_s[i];
        s0.x += a * v0.x; s0.y += a * v0.y; s0.z += a * v0.z; s0.w += a * v0.w;
        s1.x += a * v1.x; s1.y += a * v1.y; s1.z += a * v1.z; s1.w += a * v1.w;
        if (WRITE_BF) *(uint4*)(xbf + base + (size_t)i * chs) = pack8(v0, v1);
    }
    size_t kb = ((size_t)b * N_ + n) * T_ + t8 * 8;
    *(float4*)(Kt + kb) = s0;
    *(float4*)(Kt + kb + 4) = s1;
}

// ---------------------------------------------------------------------------
// Kernel 2: KW1[b,t,r] = sum_n Kt[b,n,t]*W1[r,n]; QW2 likewise.
// Thread per (b,t); W1/W2 in LDS (broadcast reads); Kt reads coalesced in t.
// ---------------------------------------------------------------------------
__global__ __launch_bounds__(256) void k_proj(const float* __restrict__ Kt,
                                              const float* __restrict__ W1,
                                              const float* __restrict__ W2,
                                              float* __restrict__ KW1,
                                              float* __restrict__ QW2) {
    __shared__ float Ws[2 * R_ * N_];  // [0]=W1 rows, [1]=W2 rows; 24.6 KB
    for (int e = threadIdx.x; e < R_ * N_; e += 256) {
        Ws[e] = W1[e];
        Ws[R_ * N_ + e] = W2[e];
    }
    __syncthreads();
    int gt = blockIdx.x * 256 + threadIdx.x;
    if (gt >= B_ * T_) return;
    int b = gt / T_;
    int t = gt % T_;
    float a1[R_], a2[R_];
#pragma unroll
    for (int r = 0; r < R_; ++r) { a1[r] = 0.f; a2[r] = 0.f; }
    const float* kp = Kt + (size_t)b * N_ * T_ + t;
    for (int n = 0; n < N_; ++n) {
        float k = kp[(size_t)n * T_];
#pragma unroll
        for (int r = 0; r < R_; ++r) {
            a1[r] += k * Ws[r * N_ + n];
            a2[r] += k * Ws[R_ * N_ + r * N_ + n];
        }
    }
#pragma unroll
    for (int r = 0; r < R_; ++r) {
        KW1[(size_t)gt * R_ + r] = a1[r];
        QW2[(size_t)gt * R_ + r] = a2[r];
    }
}

// ---------------------------------------------------------------------------
// Kernel 3: scores -> softmax -> A (bf16). One wave per (b,t).
// ---------------------------------------------------------------------------
__global__ __launch_bounds__(64) void k_softmax(const float* __restrict__ KW1,
                                                const float* __restrict__ QW2,
                                                unsigned short* __restrict__ A) {
    int bt = blockIdx.x;
    int b = bt / T_;
    int lane = threadIdx.x;
    float kw[R_];
#pragma unroll
    for (int r = 0; r < R_; ++r) kw[r] = KW1[bt * R_ + r];
    float sc[5];
    float mx = -1e30f;
#pragma unroll
    for (int j = 0; j < 5; ++j) {
        int s = lane + j * 64;
        float v = -1e30f;
        if (s < T_) {
            const float* q = QW2 + ((size_t)b * T_ + s) * R_;
            v = 0.f;
#pragma unroll
            for (int r = 0; r < R_; ++r) v += kw[r] * q[r];
        }
        sc[j] = v;
        mx = fmaxf(mx, v);
    }
#pragma unroll
    for (int off = 32; off > 0; off >>= 1) mx = fmaxf(mx, __shfl_xor(mx, off));
    float sum = 0.f;
#pragma unroll
    for (int j = 0; j < 5; ++j) {
        int s = lane + j * 64;
        float e = (s < T_) ? __expf(sc[j] - mx) : 0.f;
        sc[j] = e;
        sum += e;
    }
#pragma unroll
    for (int off = 32; off > 0; off >>= 1) sum += __shfl_xor(sum, off);
    float inv = 1.f / sum;
#pragma unroll
    for (int j = 0; j < 5; ++j) {
        int s = lane + j * 64;
        if (s < T_) A[(size_t)bt * T_ + s] = f2bf(sc[j] * inv);
    }
}

// ---------------------------------------------------------------------------
// Kernel 4: out[b,m,t] = sum_s X[b,m,s]*A[b,t,s], mfma_f32_16x16x32_bf16.
// BM=64, BN=288 (ALL t per block -> each x byte fetched exactly once),
// BK=32, 256 thr = 4 waves (2m x 2t), wave tile 32x144 = 2x9 frags.
// 2-phase register-prefetch pipeline: next K-step's global loads issued
// right after the stage barrier, consumed at next iteration's ds_write.
// LDS rows padded to 40 bf16 (80B) -> <=2-way aliasing on ds_read_b128.
// ---------------------------------------------------------------------------
template <int XBF>
__global__ __launch_bounds__(256) void k_out(const float* __restrict__ xf,
                                             const unsigned short* __restrict__ xb,
                                             const unsigned short* __restrict__ A,
                                             float* __restrict__ out) {
    const int m0 = blockIdx.x * 64;
    const int b = blockIdx.y;

    __shared__ __align__(16) unsigned short Xs[64][40];   // [m][s]
    __shared__ __align__(16) unsigned short As[288][40];  // [t][s]

    const int tid = threadIdx.x;
    const int lane = tid & 63;
    const int wid = tid >> 6;
    const int wm = wid & 1;   // m half (32 rows)
    const int wt = wid >> 1;  // t half (144 cols)
    const int c = lane & 15;
    const int kq = lane >> 4;

    // staging: X = 256 x 16B units (1/thread); A = 1152 units (4.5/thread)
    const int xrow = tid >> 2, xch = tid & 3;
    const size_t Xoff = ((size_t)b * M_ + m0 + xrow) * T_ + xch * 8;
    const unsigned short* Ag[5];
    int Arow[5], Ach[5];
#pragma unroll
    for (int i = 0; i < 5; ++i) {
        int e = tid + i * 256;
        Arow[i] = e >> 2; Ach[i] = e & 3;
        Ag[i] = A + ((size_t)b * T_ + Arow[i]) * T_ + Ach[i] * 8;
    }
    const bool a4 = (tid < 128);  // validity of unit 4 (e<1152)

    uint4 px, pa[5];
    // prologue: step 0
    if (XBF) {
        px = *(const uint4*)(xb + Xoff);
    } else {
        float4 v0 = *(const float4*)(xf + Xoff);
        float4 v1 = *(const float4*)(xf + Xoff + 4);
        px = pack8(v0, v1);
    }
#pragma unroll
    for (int i = 0; i < 5; ++i)
        if (i < 4 || a4) pa[i] = *(const uint4*)(Ag[i]);

    f32x4 acc[2][9];
#pragma unroll
    for (int i = 0; i < 2; ++i)
#pragma unroll
        for (int j = 0; j < 9; ++j) acc[i][j] = (f32x4){0.f, 0.f, 0.f, 0.f};

    for (int step = 0; step < 9; ++step) {
        // write current regs to LDS
        *(uint4*)&Xs[xrow][xch * 8] = px;
#pragma unroll
        for (int i = 0; i < 5; ++i)
            if (i < 4 || a4) *(uint4*)&As[Arow[i]][Ach[i] * 8] = pa[i];
        __syncthreads();

        // issue next step's global loads (latency hides under MFMA phase)
        if (step < 8) {
            int sn = (step + 1) * 32;
            if (XBF) {
                px = *(const uint4*)(xb + Xoff + sn);
            } else {
                float4 v0 = *(const float4*)(xf + Xoff + sn);
                float4 v1 = *(const float4*)(xf + Xoff + sn + 4);
                px = pack8(v0, v1);
            }
#pragma unroll
            for (int i = 0; i < 5; ++i)
                if (i < 4 || a4) pa[i] = *(const uint4*)(Ag[i] + sn);
        }

        bf16x8 af[2], bfr[9];
#pragma unroll
        for (int i = 0; i < 2; ++i)
            af[i] = *(const bf16x8*)&Xs[wm * 32 + i * 16 + c][kq * 8];
#pragma unroll
        for (int j = 0; j < 9; ++j)
            bfr[j] = *(const bf16x8*)&As[wt * 144 + j * 16 + c][kq * 8];
#pragma unroll
        for (int i = 0; i < 2; ++i)
#pragma unroll
            for (int j = 0; j < 9; ++j)
                acc[i][j] = __builtin_amdgcn_mfma_f32_16x16x32_bf16(af[i], bfr[j], acc[i][j], 0, 0, 0);
        __syncthreads();
    }

    float* Ob = out + (size_t)b * M_ * T_;
#pragma unroll
    for (int i = 0; i < 2; ++i) {
#pragma unroll
        for (int j = 0; j < 9; ++j) {
            int t = wt * 144 + j * 16 + c;
#pragma unroll
            for (int r = 0; r < 4; ++r) {
                int m = m0 + wm * 32 + i * 16 + kq * 4 + r;
                Ob[(size_t)m * T_ + t] = acc[i][j][r];
            }
        }
    }
}

// ---------------------------------------------------------------------------
extern "C" void kernel_launch(void* const* d_in, const int* in_sizes, int n_in,
                              void* d_out, int out_size, void* d_ws, size_t ws_size,
                              hipStream_t stream) {
    const float* x = (const float*)d_in[0];
    const float* W1 = (const float*)d_in[1];
    const float* W2 = (const float*)d_in[2];
    const float* alpha = (const float*)d_in[3];
    float* out = (float*)d_out;

    char* ws = (char*)d_ws;
    float* Kt = (float*)ws;                      ws += (size_t)B_ * N_ * T_ * 4;
    float* KW1 = (float*)ws;                     ws += (size_t)B_ * T_ * R_ * 4;
    float* QW2 = (float*)ws;                     ws += (size_t)B_ * T_ * R_ * 4;
    unsigned short* Abf = (unsigned short*)ws;   ws += (size_t)B_ * T_ * T_ * 2;
    unsigned short* xbf = (unsigned short*)ws;
    size_t need = (size_t)(ws - (char*)d_ws) + (size_t)B_ * C_ * N_ * T_ * 2;
    const bool use_bf = (ws_size >= need);

    {
        int total = B_ * N_ * (T_ / 8);
        int blks = (total + 255) / 256;
        if (use_bf)
            k_reduce<1><<<blks, 256, 0, stream>>>(x, alpha, Kt, xbf);
        else
            k_reduce<0><<<blks, 256, 0, stream>>>(x, alpha, Kt, xbf);
    }
    {
        int total = B_ * T_;
        k_proj<<<(total + 255) / 256, 256, 0, stream>>>(Kt, W1, W2, KW1, QW2);
    }
    k_softmax<<<B_ * T_, 64, 0, stream>>>(KW1, QW2, Abf);
    {
        dim3 grid(M_ / 64, B_);  // 307 x 16
        if (use_bf)
            k_out<1><<<grid, 256, 0, stream>>>(nullptr, xbf, Abf, out);
        else
            k_out<0><<<grid, 256, 0, stream>>>(x, nullptr, Abf, out);
    }
}

// Round 4
// 447.259 us; speedup vs baseline: 1.3399x; 1.3399x over previous
//
#include <hip/hip_runtime.h>

#define B_ 16
#define C_ 64
#define N_ 307
#define T_ 288
#define R_ 10
#define M_ (C_ * N_)  // 19648 = 307*64

typedef __attribute__((ext_vector_type(8))) short bf16x8;
typedef __attribute__((ext_vector_type(4))) float f32x4;

__device__ __forceinline__ unsigned short f2bf(float f) {
    unsigned int u = __float_as_uint(f);
    unsigned int r = (u + 0x7fffu + ((u >> 16) & 1u)) >> 16;  // RNE
    return (unsigned short)r;
}
__device__ __forceinline__ unsigned int pack2(float a, float b) {
    return (unsigned int)f2bf(a) | ((unsigned int)f2bf(b) << 16);
}
__device__ __forceinline__ uint4 pack8(float4 a, float4 b) {
    uint4 w;
    w.x = pack2(a.x, a.y); w.y = pack2(a.z, a.w);
    w.z = pack2(b.x, b.y); w.w = pack2(b.z, b.w);
    return w;
}

// ---------------------------------------------------------------------------
// Kernel 1: Kt[b,n,t] = sum_i alpha[i]*x[b,i,n,t] ([n][t] layout, coalesced
// writes), plus xbf = bf16(x). Thread per (b,n,t8).
// ---------------------------------------------------------------------------
template <int WRITE_BF>
__global__ __launch_bounds__(256) void k_reduce(const float* __restrict__ x,
                                                const float* __restrict__ alpha,
                                                float* __restrict__ Kt,
                                                unsigned short* __restrict__ xbf) {
    __shared__ float a_s[C_];
    if (threadIdx.x < C_) a_s[threadIdx.x] = alpha[threadIdx.x];
    __syncthreads();
    const int T8 = T_ / 8;  // 36
    int idx = blockIdx.x * blockDim.x + threadIdx.x;
    const int total = B_ * N_ * T8;
    if (idx >= total) return;
    int t8 = idx % T8;
    int n = (idx / T8) % N_;
    int b = idx / (N_ * T8);
    const size_t chs = (size_t)N_ * T_;
    size_t base = ((size_t)(b * C_) * N_ + n) * T_ + t8 * 8;
    float4 s0 = {0.f, 0.f, 0.f, 0.f}, s1 = {0.f, 0.f, 0.f, 0.f};
#pragma unroll 4
    for (int i = 0; i < C_; ++i) {
        float4 v0 = *(const float4*)(x + base + (size_t)i * chs);
        float4 v1 = *(const float4*)(x + base + (size_t)i * chs + 4);
        float a = a_s[i];
        s0.x += a * v0.x; s0.y += a * v0.y; s0.z += a * v0.z; s0.w += a * v0.w;
        s1.x += a * v1.x; s1.y += a * v1.y; s1.z += a * v1.z; s1.w += a * v1.w;
        if (WRITE_BF) *(uint4*)(xbf + base + (size_t)i * chs) = pack8(v0, v1);
    }
    size_t kb = ((size_t)b * N_ + n) * T_ + t8 * 8;
    *(float4*)(Kt + kb) = s0;
    *(float4*)(Kt + kb + 4) = s1;
}

// ---------------------------------------------------------------------------
// Kernel 2: KW1[b,t,r] = sum_n Kt[b,n,t]*W1[r,n]; QW2 likewise.
// Thread per (b,t); W1/W2 in LDS; Kt reads coalesced in t.
// ---------------------------------------------------------------------------
__global__ __launch_bounds__(256) void k_proj(const float* __restrict__ Kt,
                                              const float* __restrict__ W1,
                                              const float* __restrict__ W2,
                                              float* __restrict__ KW1,
                                              float* __restrict__ QW2) {
    __shared__ float Ws[2 * R_ * N_];
    for (int e = threadIdx.x; e < R_ * N_; e += 256) {
        Ws[e] = W1[e];
        Ws[R_ * N_ + e] = W2[e];
    }
    __syncthreads();
    int gt = blockIdx.x * 256 + threadIdx.x;
    if (gt >= B_ * T_) return;
    int b = gt / T_;
    int t = gt % T_;
    float a1[R_], a2[R_];
#pragma unroll
    for (int r = 0; r < R_; ++r) { a1[r] = 0.f; a2[r] = 0.f; }
    const float* kp = Kt + (size_t)b * N_ * T_ + t;
    for (int n = 0; n < N_; ++n) {
        float k = kp[(size_t)n * T_];
#pragma unroll
        for (int r = 0; r < R_; ++r) {
            a1[r] += k * Ws[r * N_ + n];
            a2[r] += k * Ws[R_ * N_ + r * N_ + n];
        }
    }
#pragma unroll
    for (int r = 0; r < R_; ++r) {
        KW1[(size_t)gt * R_ + r] = a1[r];
        QW2[(size_t)gt * R_ + r] = a2[r];
    }
}

// ---------------------------------------------------------------------------
// Kernel 3: scores -> softmax -> A (bf16). One wave per (b,t).
// ---------------------------------------------------------------------------
__global__ __launch_bounds__(64) void k_softmax(const float* __restrict__ KW1,
                                                const float* __restrict__ QW2,
                                                unsigned short* __restrict__ A) {
    int bt = blockIdx.x;
    int b = bt / T_;
    int lane = threadIdx.x;
    float kw[R_];
#pragma unroll
    for (int r = 0; r < R_; ++r) kw[r] = KW1[bt * R_ + r];
    float sc[5];
    float mx = -1e30f;
#pragma unroll
    for (int j = 0; j < 5; ++j) {
        int s = lane + j * 64;
        float v = -1e30f;
        if (s < T_) {
            const float* q = QW2 + ((size_t)b * T_ + s) * R_;
            v = 0.f;
#pragma unroll
            for (int r = 0; r < R_; ++r) v += kw[r] * q[r];
        }
        sc[j] = v;
        mx = fmaxf(mx, v);
    }
#pragma unroll
    for (int off = 32; off > 0; off >>= 1) mx = fmaxf(mx, __shfl_xor(mx, off));
    float sum = 0.f;
#pragma unroll
    for (int j = 0; j < 5; ++j) {
        int s = lane + j * 64;
        float e = (s < T_) ? __expf(sc[j] - mx) : 0.f;
        sc[j] = e;
        sum += e;
    }
#pragma unroll
    for (int off = 32; off > 0; off >>= 1) sum += __shfl_xor(sum, off);
    float inv = 1.f / sum;
#pragma unroll
    for (int j = 0; j < 5; ++j) {
        int s = lane + j * 64;
        if (s < T_) A[(size_t)bt * T_ + s] = f2bf(sc[j] * inv);
    }
}

// ---------------------------------------------------------------------------
// Kernel 4: out[b,m,t] = sum_s X[b,m,s]*A[b,t,s], mfma_f32_16x16x32_bf16.
// Round-2 geometry (BM=64, BN=96, BK=32, 4 waves 2x2, 12.8KB LDS, high occ)
// + register prefetch pipeline (next step's loads issued right after the
// stage barrier, consumed at next ds_write -> latency hidden under MFMA+TLP)
// + grid(t=3, m=307, b=16): the 3 t-blocks sharing an x-panel are dispatch-
// adjacent -> co-resident -> panel fetched from HBM once (L3/L2 shared).
// LDS rows padded to 40 bf16 (80B): b128 footprint = 2 accesses/bank.
// ---------------------------------------------------------------------------
template <int XBF>
__global__ __launch_bounds__(256) void k_out(const float* __restrict__ xf,
                                             const unsigned short* __restrict__ xb,
                                             const unsigned short* __restrict__ A,
                                             float* __restrict__ out) {
    const int t0 = blockIdx.x * 96;
    const int m0 = blockIdx.y * 64;
    const int b = blockIdx.z;

    __shared__ __align__(16) unsigned short Xs[64][40];  // [m][s]
    __shared__ __align__(16) unsigned short As[96][40];  // [t][s]

    const int tid = threadIdx.x;
    const int lane = tid & 63;
    const int wid = tid >> 6;
    const int wm = wid & 1;   // m half (32 rows)
    const int wt = wid >> 1;  // t half (48 cols)
    const int c = lane & 15;
    const int kq = lane >> 4;

    // staging: X = 256 x 16B units (1/thread); A = 192 threads x 2 units
    const int xr = tid >> 2, xq = tid & 3;
    const size_t Xoff = ((size_t)b * M_ + m0 + xr) * T_ + xq * 8;
    const int ar = tid >> 1, ah = tid & 1;
    const size_t Aoff = ((size_t)b * T_ + t0 + ar) * T_ + ah * 16;
    const bool astage = (tid < 192);

    uint4 px, pa0, pa1;
    // prologue: step 0 loads
    if (XBF) {
        px = *(const uint4*)(xb + Xoff);
    } else {
        float4 v0 = *(const float4*)(xf + Xoff);
        float4 v1 = *(const float4*)(xf + Xoff + 4);
        px = pack8(v0, v1);
    }
    if (astage) {
        pa0 = *(const uint4*)(A + Aoff);
        pa1 = *(const uint4*)(A + Aoff + 8);
    }

    f32x4 acc[2][3];
#pragma unroll
    for (int i = 0; i < 2; ++i)
#pragma unroll
        for (int j = 0; j < 3; ++j) acc[i][j] = (f32x4){0.f, 0.f, 0.f, 0.f};

    for (int step = 0; step < 9; ++step) {
        // commit prefetched regs to LDS
        *(uint4*)&Xs[xr][xq * 8] = px;
        if (astage) {
            *(uint4*)&As[ar][ah * 16] = pa0;
            *(uint4*)&As[ar][ah * 16 + 8] = pa1;
        }
        __syncthreads();

        // issue next step's global loads; latency hides under MFMA phase
        if (step < 8) {
            int sn = (step + 1) * 32;
            if (XBF) {
                px = *(const uint4*)(xb + Xoff + sn);
            } else {
                float4 v0 = *(const float4*)(xf + Xoff + sn);
                float4 v1 = *(const float4*)(xf + Xoff + sn + 4);
                px = pack8(v0, v1);
            }
            if (astage) {
                pa0 = *(const uint4*)(A + Aoff + sn);
                pa1 = *(const uint4*)(A + Aoff + sn + 8);
            }
        }

        bf16x8 af[2], bfr[3];
#pragma unroll
        for (int i = 0; i < 2; ++i)
            af[i] = *(const bf16x8*)&Xs[wm * 32 + i * 16 + c][kq * 8];
#pragma unroll
        for (int j = 0; j < 3; ++j)
            bfr[j] = *(const bf16x8*)&As[wt * 48 + j * 16 + c][kq * 8];
#pragma unroll
        for (int i = 0; i < 2; ++i)
#pragma unroll
            for (int j = 0; j < 3; ++j)
                acc[i][j] = __builtin_amdgcn_mfma_f32_16x16x32_bf16(af[i], bfr[j], acc[i][j], 0, 0, 0);
        __syncthreads();
    }

    float* Ob = out + (size_t)b * M_ * T_;
#pragma unroll
    for (int i = 0; i < 2; ++i) {
#pragma unroll
        for (int j = 0; j < 3; ++j) {
            int t = t0 + wt * 48 + j * 16 + c;
#pragma unroll
            for (int r = 0; r < 4; ++r) {
                int m = m0 + wm * 32 + i * 16 + kq * 4 + r;
                Ob[(size_t)m * T_ + t] = acc[i][j][r];
            }
        }
    }
}

// ---------------------------------------------------------------------------
extern "C" void kernel_launch(void* const* d_in, const int* in_sizes, int n_in,
                              void* d_out, int out_size, void* d_ws, size_t ws_size,
                              hipStream_t stream) {
    const float* x = (const float*)d_in[0];
    const float* W1 = (const float*)d_in[1];
    const float* W2 = (const float*)d_in[2];
    const float* alpha = (const float*)d_in[3];
    float* out = (float*)d_out;

    char* ws = (char*)d_ws;
    float* Kt = (float*)ws;                      ws += (size_t)B_ * N_ * T_ * 4;
    float* KW1 = (float*)ws;                     ws += (size_t)B_ * T_ * R_ * 4;
    float* QW2 = (float*)ws;                     ws += (size_t)B_ * T_ * R_ * 4;
    unsigned short* Abf = (unsigned short*)ws;   ws += (size_t)B_ * T_ * T_ * 2;
    unsigned short* xbf = (unsigned short*)ws;
    size_t need = (size_t)(ws - (char*)d_ws) + (size_t)B_ * C_ * N_ * T_ * 2;
    const bool use_bf = (ws_size >= need);

    {
        int total = B_ * N_ * (T_ / 8);
        int blks = (total + 255) / 256;
        if (use_bf)
            k_reduce<1><<<blks, 256, 0, stream>>>(x, alpha, Kt, xbf);
        else
            k_reduce<0><<<blks, 256, 0, stream>>>(x, alpha, Kt, xbf);
    }
    {
        int total = B_ * T_;
        k_proj<<<(total + 255) / 256, 256, 0, stream>>>(Kt, W1, W2, KW1, QW2);
    }
    k_softmax<<<B_ * T_, 64, 0, stream>>>(KW1, QW2, Abf);
    {
        dim3 grid(T_ / 96, M_ / 64, B_);  // 3 x 307 x 16
        if (use_bf)
            k_out<1><<<grid, 256, 0, stream>>>(nullptr, xbf, Abf, out);
        else
            k_out<0><<<grid, 256, 0, stream>>>(x, nullptr, Abf, out);
    }
}

// Round 5
// 368.654 us; speedup vs baseline: 1.6256x; 1.2132x over previous
//
#include <hip/hip_runtime.h>

#define B_ 16
#define C_ 64
#define N_ 307
#define T_ 288
#define R_ 10
#define M_ (C_ * N_)  // 19648 = 307*64

typedef __attribute__((ext_vector_type(8))) short bf16x8;
typedef __attribute__((ext_vector_type(4))) float f32x4;

__device__ __forceinline__ unsigned short f2bf(float f) {
    unsigned int u = __float_as_uint(f);
    unsigned int r = (u + 0x7fffu + ((u >> 16) & 1u)) >> 16;  // RNE
    return (unsigned short)r;
}
__device__ __forceinline__ unsigned int pack2(float a, float b) {
    return (unsigned int)f2bf(a) | ((unsigned int)f2bf(b) << 16);
}
__device__ __forceinline__ uint4 pack8(float4 a, float4 b) {
    uint4 w;
    w.x = pack2(a.x, a.y); w.y = pack2(a.z, a.w);
    w.z = pack2(b.x, b.y); w.w = pack2(b.z, b.w);
    return w;
}

// ---------------------------------------------------------------------------
// Kernel 1: Kt[b,n,t] = sum_i alpha[i]*x[b,i,n,t] (coalesced writes), plus
// xbf = bf16(x). Pure streaming: this kernel carries the conversion bytes
// because it runs nearest to peak BW.
// ---------------------------------------------------------------------------
template <int WRITE_BF>
__global__ __launch_bounds__(256) void k_reduce(const float* __restrict__ x,
                                                const float* __restrict__ alpha,
                                                float* __restrict__ Kt,
                                                unsigned short* __restrict__ xbf) {
    __shared__ float a_s[C_];
    if (threadIdx.x < C_) a_s[threadIdx.x] = alpha[threadIdx.x];
    __syncthreads();
    const int T8 = T_ / 8;  // 36
    int idx = blockIdx.x * blockDim.x + threadIdx.x;
    const int total = B_ * N_ * T8;
    if (idx >= total) return;
    int t8 = idx % T8;
    int n = (idx / T8) % N_;
    int b = idx / (N_ * T8);
    const size_t chs = (size_t)N_ * T_;
    size_t base = ((size_t)(b * C_) * N_ + n) * T_ + t8 * 8;
    float4 s0 = {0.f, 0.f, 0.f, 0.f}, s1 = {0.f, 0.f, 0.f, 0.f};
#pragma unroll 4
    for (int i = 0; i < C_; ++i) {
        float4 v0 = *(const float4*)(x + base + (size_t)i * chs);
        float4 v1 = *(const float4*)(x + base + (size_t)i * chs + 4);
        float a = a_s[i];
        s0.x += a * v0.x; s0.y += a * v0.y; s0.z += a * v0.z; s0.w += a * v0.w;
        s1.x += a * v1.x; s1.y += a * v1.y; s1.z += a * v1.z; s1.w += a * v1.w;
        if (WRITE_BF) *(uint4*)(xbf + base + (size_t)i * chs) = pack8(v0, v1);
    }
    size_t kb = ((size_t)b * N_ + n) * T_ + t8 * 8;
    *(float4*)(Kt + kb) = s0;
    *(float4*)(Kt + kb + 4) = s1;
}

// ---------------------------------------------------------------------------
// Kernel 2: KW1[b,t,r], QW2[b,t,r] from Kt[b,n,t].
// Block per (b, t-chunk of 32) = 144 blocks; 8-way n-split + LDS reduce.
// ---------------------------------------------------------------------------
#define PG 8
__global__ __launch_bounds__(256) void k_proj(const float* __restrict__ Kt,
                                              const float* __restrict__ W1,
                                              const float* __restrict__ W2,
                                              float* __restrict__ KW1,
                                              float* __restrict__ QW2) {
    __shared__ float Ws[2 * R_ * N_];          // 24.6 KB
    __shared__ float part[PG][32][2 * R_];     // 20.5 KB
    for (int e = threadIdx.x; e < R_ * N_; e += 256) {
        Ws[e] = W1[e];
        Ws[R_ * N_ + e] = W2[e];
    }
    __syncthreads();
    int b = blockIdx.x / (T_ / 32);
    int tc = blockIdx.x % (T_ / 32);
    int t0 = tc * 32;
    int g = threadIdx.x >> 5;
    int tl = threadIdx.x & 31;
    int n0 = g * 38 + (g < 3 ? g : 3);
    int n1 = n0 + 38 + (g < 3 ? 1 : 0);
    float a[2 * R_];
#pragma unroll
    for (int r = 0; r < 2 * R_; ++r) a[r] = 0.f;
    const float* kp = Kt + (size_t)b * N_ * T_ + t0 + tl;
    for (int n = n0; n < n1; ++n) {
        float kv = kp[(size_t)n * T_];
#pragma unroll
        for (int r = 0; r < R_; ++r) {
            a[r] += kv * Ws[r * N_ + n];
            a[R_ + r] += kv * Ws[R_ * N_ + r * N_ + n];
        }
    }
#pragma unroll
    for (int r = 0; r < 2 * R_; ++r) part[g][tl][r] = a[r];
    __syncthreads();
    for (int o = threadIdx.x; o < 32 * 2 * R_; o += 256) {
        int tl2 = o / (2 * R_);
        int rr = o % (2 * R_);
        float s = 0.f;
#pragma unroll
        for (int gg = 0; gg < PG; ++gg) s += part[gg][tl2][rr];
        int t = t0 + tl2;
        if (rr < R_) KW1[((size_t)b * T_ + t) * R_ + rr] = s;
        else         QW2[((size_t)b * T_ + t) * R_ + rr - R_] = s;
    }
}

// ---------------------------------------------------------------------------
// Kernel 3: scores -> softmax -> A (bf16). One wave per (b,t).
// ---------------------------------------------------------------------------
__global__ __launch_bounds__(64) void k_softmax(const float* __restrict__ KW1,
                                                const float* __restrict__ QW2,
                                                unsigned short* __restrict__ A) {
    int bt = blockIdx.x;
    int b = bt / T_;
    int lane = threadIdx.x;
    float kw[R_];
#pragma unroll
    for (int r = 0; r < R_; ++r) kw[r] = KW1[bt * R_ + r];
    float sc[5];
    float mx = -1e30f;
#pragma unroll
    for (int j = 0; j < 5; ++j) {
        int s = lane + j * 64;
        float v = -1e30f;
        if (s < T_) {
            const float* q = QW2 + ((size_t)b * T_ + s) * R_;
            v = 0.f;
#pragma unroll
            for (int r = 0; r < R_; ++r) v += kw[r] * q[r];
        }
        sc[j] = v;
        mx = fmaxf(mx, v);
    }
#pragma unroll
    for (int off = 32; off > 0; off >>= 1) mx = fmaxf(mx, __shfl_xor(mx, off));
    float sum = 0.f;
#pragma unroll
    for (int j = 0; j < 5; ++j) {
        int s = lane + j * 64;
        float e = (s < T_) ? __expf(sc[j] - mx) : 0.f;
        sc[j] = e;
        sum += e;
    }
#pragma unroll
    for (int off = 32; off > 0; off >>= 1) sum += __shfl_xor(sum, off);
    float inv = 1.f / sum;
#pragma unroll
    for (int j = 0; j < 5; ++j) {
        int s = lane + j * 64;
        if (s < T_) A[(size_t)bt * T_ + s] = f2bf(sc[j] * inv);
    }
}

// ---------------------------------------------------------------------------
// Kernel 4: out[b,m,t] = sum_s X[b,m,s]*A[b,t,s], mfma_f32_16x16x32_bf16.
// Block = 64 m-rows x ALL 288 t (3 chunks of 96 inside). X panel staged to
// LDS ONCE (1 barrier total) -> each x byte fetched exactly once grid-wide.
// A read directly from global (166 KB/batch, L2-resident) as B-fragments:
// 16 rows x 64B contiguous per load. No barriers in the compute loops ->
// compiler software-pipelines the A-loads under MFMA.
// LDS row stride 296 bf16 = 148 dw (= 4 mod 8): 2-way bank aliasing (free).
// ---------------------------------------------------------------------------
template <int XBF>
__global__ __launch_bounds__(256, 4) void k_out(const float* __restrict__ xf,
                                                const unsigned short* __restrict__ xb,
                                                const unsigned short* __restrict__ A,
                                                float* __restrict__ out) {
    const int m0 = blockIdx.x * 64;
    const int b = blockIdx.y;

    __shared__ __align__(16) unsigned short Xs[64][296];  // 37,888 B

    const int tid = threadIdx.x;
    const int lane = tid & 63;
    const int wid = tid >> 6;
    const int wm = wid & 1;   // m half (32 rows)
    const int wt = wid >> 1;  // t half (48 of the 96-chunk)
    const int c = lane & 15;
    const int kq = lane >> 4;

    // ---- stage X panel (64 x 288) once: 2304 8-elem units, 9 per thread ----
    {
        const size_t Xg = ((size_t)b * M_ + m0) * T_;
#pragma unroll
        for (int u = 0; u < 9; ++u) {
            int e = tid + u * 256;
            int row = e / 36;
            int ch = e % 36;
            if (XBF) {
                *(uint4*)&Xs[row][ch * 8] = *(const uint4*)(xb + Xg + (size_t)row * T_ + ch * 8);
            } else {
                float4 v0 = *(const float4*)(xf + Xg + (size_t)row * T_ + ch * 8);
                float4 v1 = *(const float4*)(xf + Xg + (size_t)row * T_ + ch * 8 + 4);
                *(uint4*)&Xs[row][ch * 8] = pack8(v0, v1);
            }
        }
    }
    __syncthreads();

    const unsigned short* Ab = A + (size_t)b * T_ * T_;
    float* Ob = out + ((size_t)b * M_ + m0) * T_;

    for (int chunk = 0; chunk < 3; ++chunk) {
        const int tb = chunk * 96 + wt * 48;
        f32x4 acc[2][3];
#pragma unroll
        for (int i = 0; i < 2; ++i)
#pragma unroll
            for (int j = 0; j < 3; ++j) acc[i][j] = (f32x4){0.f, 0.f, 0.f, 0.f};

#pragma unroll
        for (int k = 0; k < 9; ++k) {
            const int s0 = k * 32;
            bf16x8 a0 = *(const bf16x8*)&Xs[wm * 32 + c][s0 + kq * 8];
            bf16x8 a1 = *(const bf16x8*)&Xs[wm * 32 + 16 + c][s0 + kq * 8];
            const unsigned short* ap = Ab + (size_t)(tb + c) * T_ + s0 + kq * 8;
            bf16x8 b0 = *(const bf16x8*)(ap);
            bf16x8 b1 = *(const bf16x8*)(ap + 16 * T_);
            bf16x8 b2 = *(const bf16x8*)(ap + 32 * T_);
            acc[0][0] = __builtin_amdgcn_mfma_f32_16x16x32_bf16(a0, b0, acc[0][0], 0, 0, 0);
            acc[1][0] = __builtin_amdgcn_mfma_f32_16x16x32_bf16(a1, b0, acc[1][0], 0, 0, 0);
            acc[0][1] = __builtin_amdgcn_mfma_f32_16x16x32_bf16(a0, b1, acc[0][1], 0, 0, 0);
            acc[1][1] = __builtin_amdgcn_mfma_f32_16x16x32_bf16(a1, b1, acc[1][1], 0, 0, 0);
            acc[0][2] = __builtin_amdgcn_mfma_f32_16x16x32_bf16(a0, b2, acc[0][2], 0, 0, 0);
            acc[1][2] = __builtin_amdgcn_mfma_f32_16x16x32_bf16(a1, b2, acc[1][2], 0, 0, 0);
        }

#pragma unroll
        for (int i = 0; i < 2; ++i) {
#pragma unroll
            for (int j = 0; j < 3; ++j) {
                int t = tb + j * 16 + c;
#pragma unroll
                for (int r = 0; r < 4; ++r) {
                    int m = wm * 32 + i * 16 + kq * 4 + r;
                    Ob[(size_t)m * T_ + t] = acc[i][j][r];
                }
            }
        }
    }
}

// ---------------------------------------------------------------------------
extern "C" void kernel_launch(void* const* d_in, const int* in_sizes, int n_in,
                              void* d_out, int out_size, void* d_ws, size_t ws_size,
                              hipStream_t stream) {
    const float* x = (const float*)d_in[0];
    const float* W1 = (const float*)d_in[1];
    const float* W2 = (const float*)d_in[2];
    const float* alpha = (const float*)d_in[3];
    float* out = (float*)d_out;

    char* ws = (char*)d_ws;
    float* Kt = (float*)ws;                      ws += (size_t)B_ * N_ * T_ * 4;
    float* KW1 = (float*)ws;                     ws += (size_t)B_ * T_ * R_ * 4;
    float* QW2 = (float*)ws;                     ws += (size_t)B_ * T_ * R_ * 4;
    unsigned short* Abf = (unsigned short*)ws;   ws += (size_t)B_ * T_ * T_ * 2;
    unsigned short* xbf = (unsigned short*)ws;
    size_t need = (size_t)(ws - (char*)d_ws) + (size_t)B_ * C_ * N_ * T_ * 2;
    const bool use_bf = (ws_size >= need);

    {
        int total = B_ * N_ * (T_ / 8);
        int blks = (total + 255) / 256;
        if (use_bf)
            k_reduce<1><<<blks, 256, 0, stream>>>(x, alpha, Kt, xbf);
        else
            k_reduce<0><<<blks, 256, 0, stream>>>(x, alpha, Kt, xbf);
    }
    k_proj<<<B_ * (T_ / 32), 256, 0, stream>>>(Kt, W1, W2, KW1, QW2);
    k_softmax<<<B_ * T_, 64, 0, stream>>>(KW1, QW2, Abf);
    {
        dim3 grid(M_ / 64, B_);  // 307 x 16
        if (use_bf)
            k_out<1><<<grid, 256, 0, stream>>>(nullptr, xbf, Abf, out);
        else
            k_out<0><<<grid, 256, 0, stream>>>(x, nullptr, Abf, out);
    }
}

// Round 6
// 326.194 us; speedup vs baseline: 1.8372x; 1.1302x over previous
//
#include <hip/hip_runtime.h>

#define B_ 16
#define C_ 64
#define N_ 307
#define T_ 288
#define R_ 10
#define M_ (C_ * N_)   // 19648 = 307*64
#define TT_ (T_ / 16)  // 18 t-tiles
#define ST_ (T_ / 32)  // 9 k-tiles

typedef __attribute__((ext_vector_type(8))) short bf16x8;
typedef __attribute__((ext_vector_type(4))) float f32x4;

__device__ __forceinline__ unsigned short f2bf(float f) {
    unsigned int u = __float_as_uint(f);
    unsigned int r = (u + 0x7fffu + ((u >> 16) & 1u)) >> 16;  // RNE
    return (unsigned short)r;
}
__device__ __forceinline__ unsigned int pack2(float a, float b) {
    return (unsigned int)f2bf(a) | ((unsigned int)f2bf(b) << 16);
}
__device__ __forceinline__ uint4 pack8(float4 a, float4 b) {
    uint4 w;
    w.x = pack2(a.x, a.y); w.y = pack2(a.z, a.w);
    w.z = pack2(b.x, b.y); w.w = pack2(b.z, b.w);
    return w;
}

// ---------------------------------------------------------------------------
// Kernel 1: Kt[b,n,t] = sum_i alpha[i]*x[b,i,n,t] (coalesced writes), plus
// xbf = bf16(x) echo (L3-resident for k_out).
// ---------------------------------------------------------------------------
template <int WRITE_BF>
__global__ __launch_bounds__(256) void k_reduce(const float* __restrict__ x,
                                                const float* __restrict__ alpha,
                                                float* __restrict__ Kt,
                                                unsigned short* __restrict__ xbf) {
    __shared__ float a_s[C_];
    if (threadIdx.x < C_) a_s[threadIdx.x] = alpha[threadIdx.x];
    __syncthreads();
    const int T8 = T_ / 8;  // 36
    int idx = blockIdx.x * blockDim.x + threadIdx.x;
    const int total = B_ * N_ * T8;
    if (idx >= total) return;
    int t8 = idx % T8;
    int n = (idx / T8) % N_;
    int b = idx / (N_ * T8);
    const size_t chs = (size_t)N_ * T_;
    size_t base = ((size_t)(b * C_) * N_ + n) * T_ + t8 * 8;
    float4 s0 = {0.f, 0.f, 0.f, 0.f}, s1 = {0.f, 0.f, 0.f, 0.f};
#pragma unroll 4
    for (int i = 0; i < C_; ++i) {
        float4 v0 = *(const float4*)(x + base + (size_t)i * chs);
        float4 v1 = *(const float4*)(x + base + (size_t)i * chs + 4);
        float a = a_s[i];
        s0.x += a * v0.x; s0.y += a * v0.y; s0.z += a * v0.z; s0.w += a * v0.w;
        s1.x += a * v1.x; s1.y += a * v1.y; s1.z += a * v1.z; s1.w += a * v1.w;
        if (WRITE_BF) *(uint4*)(xbf + base + (size_t)i * chs) = pack8(v0, v1);
    }
    size_t kb = ((size_t)b * N_ + n) * T_ + t8 * 8;
    *(float4*)(Kt + kb) = s0;
    *(float4*)(Kt + kb + 4) = s1;
}

// ---------------------------------------------------------------------------
// Kernel 2: KW1[b,t,r], QW2[b,t,r] from Kt[b,n,t]. 144 blocks, 8-way n-split.
// ---------------------------------------------------------------------------
#define PG 8
__global__ __launch_bounds__(256) void k_proj(const float* __restrict__ Kt,
                                              const float* __restrict__ W1,
                                              const float* __restrict__ W2,
                                              float* __restrict__ KW1,
                                              float* __restrict__ QW2) {
    __shared__ float Ws[2 * R_ * N_];
    __shared__ float part[PG][32][2 * R_];
    for (int e = threadIdx.x; e < R_ * N_; e += 256) {
        Ws[e] = W1[e];
        Ws[R_ * N_ + e] = W2[e];
    }
    __syncthreads();
    int b = blockIdx.x / (T_ / 32);
    int tc = blockIdx.x % (T_ / 32);
    int t0 = tc * 32;
    int g = threadIdx.x >> 5;
    int tl = threadIdx.x & 31;
    int n0 = g * 38 + (g < 3 ? g : 3);
    int n1 = n0 + 38 + (g < 3 ? 1 : 0);
    float a[2 * R_];
#pragma unroll
    for (int r = 0; r < 2 * R_; ++r) a[r] = 0.f;
    const float* kp = Kt + (size_t)b * N_ * T_ + t0 + tl;
    for (int n = n0; n < n1; ++n) {
        float kv = kp[(size_t)n * T_];
#pragma unroll
        for (int r = 0; r < R_; ++r) {
            a[r] += kv * Ws[r * N_ + n];
            a[R_ + r] += kv * Ws[R_ * N_ + r * N_ + n];
        }
    }
#pragma unroll
    for (int r = 0; r < 2 * R_; ++r) part[g][tl][r] = a[r];
    __syncthreads();
    for (int o = threadIdx.x; o < 32 * 2 * R_; o += 256) {
        int tl2 = o / (2 * R_);
        int rr = o % (2 * R_);
        float s = 0.f;
#pragma unroll
        for (int gg = 0; gg < PG; ++gg) s += part[gg][tl2][rr];
        int t = t0 + tl2;
        if (rr < R_) KW1[((size_t)b * T_ + t) * R_ + rr] = s;
        else         QW2[((size_t)b * T_ + t) * R_ + rr - R_] = s;
    }
}

// ---------------------------------------------------------------------------
// Kernel 3: scores -> softmax -> Apk in MFMA B-fragment layout:
//   Apk[((b*18 + tt)*9 + st)*512 + (tl + 16*q)*8 + e] = A[b][t=tt*16+tl][s=st*32+q*8+e]
// so k_out loads each 1KB fragment as one coalesced dwordx4/lane.
// One wave per (b,t).
// ---------------------------------------------------------------------------
__global__ __launch_bounds__(64) void k_softmax(const float* __restrict__ KW1,
                                                const float* __restrict__ QW2,
                                                unsigned short* __restrict__ Apk) {
    __shared__ __align__(16) unsigned short sm[T_];
    int bt = blockIdx.x;
    int b = bt / T_;
    int t = bt % T_;
    int lane = threadIdx.x;
    float kw[R_];
#pragma unroll
    for (int r = 0; r < R_; ++r) kw[r] = KW1[bt * R_ + r];
    float sc[5];
    float mx = -1e30f;
#pragma unroll
    for (int j = 0; j < 5; ++j) {
        int s = lane + j * 64;
        float v = -1e30f;
        if (s < T_) {
            const float* q = QW2 + ((size_t)b * T_ + s) * R_;
            v = 0.f;
#pragma unroll
            for (int r = 0; r < R_; ++r) v += kw[r] * q[r];
        }
        sc[j] = v;
        mx = fmaxf(mx, v);
    }
#pragma unroll
    for (int off = 32; off > 0; off >>= 1) mx = fmaxf(mx, __shfl_xor(mx, off));
    float sum = 0.f;
#pragma unroll
    for (int j = 0; j < 5; ++j) {
        int s = lane + j * 64;
        float e = (s < T_) ? __expf(sc[j] - mx) : 0.f;
        sc[j] = e;
        sum += e;
    }
#pragma unroll
    for (int off = 32; off > 0; off >>= 1) sum += __shfl_xor(sum, off);
    float inv = 1.f / sum;
#pragma unroll
    for (int j = 0; j < 5; ++j) {
        int s = lane + j * 64;
        if (s < T_) sm[s] = f2bf(sc[j] * inv);
    }
    __syncthreads();
    if (lane < 36) {
        int st = lane >> 2, q = lane & 3;
        uint4 v = *(const uint4*)&sm[st * 32 + q * 8];
        int tt = t >> 4, tl = t & 15;
        size_t dst = ((((size_t)b * TT_ + tt) * ST_ + st) * 64 + tl + 16 * q) * 8;
        *(uint4*)(Apk + dst) = v;
    }
}

// ---------------------------------------------------------------------------
// Kernel 4: out[b,m,t] = sum_s X[b,m,s]*A[b,t,s], mfma_f32_16x16x32_bf16.
// Block = 64m x 288t; X panel staged to LDS once (x fetched once grid-wide).
// A read from Apk (fragment layout): 1 coalesced 16B/lane load per fragment,
// with explicit 2-deep register prefetch in a barrier-free unrolled loop.
// ---------------------------------------------------------------------------
template <int XBF>
__global__ __launch_bounds__(256, 4) void k_out(const float* __restrict__ xf,
                                                const unsigned short* __restrict__ xb,
                                                const unsigned short* __restrict__ Apk,
                                                float* __restrict__ out) {
    const int m0 = blockIdx.x * 64;
    const int b = blockIdx.y;

    __shared__ __align__(16) unsigned short Xs[64][296];  // 37,888 B

    const int tid = threadIdx.x;
    const int lane = tid & 63;
    const int wid = tid >> 6;
    const int wm = wid & 1;   // m half (32 rows)
    const int wt = wid >> 1;  // t half (48 of each 96-chunk)
    const int c = lane & 15;
    const int kq = lane >> 4;

    // ---- stage X panel (64 x 288) once ----
    {
        const size_t Xg = ((size_t)b * M_ + m0) * T_;
#pragma unroll
        for (int u = 0; u < 9; ++u) {
            int e = tid + u * 256;
            int row = e / 36;
            int ch = e % 36;
            if (XBF) {
                *(uint4*)&Xs[row][ch * 8] = *(const uint4*)(xb + Xg + (size_t)row * T_ + ch * 8);
            } else {
                float4 v0 = *(const float4*)(xf + Xg + (size_t)row * T_ + ch * 8);
                float4 v1 = *(const float4*)(xf + Xg + (size_t)row * T_ + ch * 8 + 4);
                *(uint4*)&Xs[row][ch * 8] = pack8(v0, v1);
            }
        }
    }
    __syncthreads();

    float* Ob = out + ((size_t)b * M_ + m0) * T_;

    for (int chunk = 0; chunk < 3; ++chunk) {
        const int tt0 = chunk * 6 + wt * 3;  // first of 3 t-tiles for this wave
        const unsigned short* bb[3];
#pragma unroll
        for (int j = 0; j < 3; ++j)
            bb[j] = Apk + (((size_t)b * TT_ + tt0 + j) * ST_) * 512 + (size_t)lane * 8;

        f32x4 acc[2][3];
#pragma unroll
        for (int i = 0; i < 2; ++i)
#pragma unroll
            for (int j = 0; j < 3; ++j) acc[i][j] = (f32x4){0.f, 0.f, 0.f, 0.f};

        bf16x8 cur[3], nxt[3];
#pragma unroll
        for (int j = 0; j < 3; ++j) cur[j] = *(const bf16x8*)(bb[j]);
#pragma unroll
        for (int j = 0; j < 3; ++j) nxt[j] = *(const bf16x8*)(bb[j] + 512);

#pragma unroll
        for (int k = 0; k < 9; ++k) {
            bf16x8 tmp[3];
            if (k + 2 < 9) {
#pragma unroll
                for (int j = 0; j < 3; ++j)
                    tmp[j] = *(const bf16x8*)(bb[j] + (size_t)(k + 2) * 512);
            }
            bf16x8 a0 = *(const bf16x8*)&Xs[wm * 32 + c][k * 32 + kq * 8];
            bf16x8 a1 = *(const bf16x8*)&Xs[wm * 32 + 16 + c][k * 32 + kq * 8];
            acc[0][0] = __builtin_amdgcn_mfma_f32_16x16x32_bf16(a0, cur[0], acc[0][0], 0, 0, 0);
            acc[1][0] = __builtin_amdgcn_mfma_f32_16x16x32_bf16(a1, cur[0], acc[1][0], 0, 0, 0);
            acc[0][1] = __builtin_amdgcn_mfma_f32_16x16x32_bf16(a0, cur[1], acc[0][1], 0, 0, 0);
            acc[1][1] = __builtin_amdgcn_mfma_f32_16x16x32_bf16(a1, cur[1], acc[1][1], 0, 0, 0);
            acc[0][2] = __builtin_amdgcn_mfma_f32_16x16x32_bf16(a0, cur[2], acc[0][2], 0, 0, 0);
            acc[1][2] = __builtin_amdgcn_mfma_f32_16x16x32_bf16(a1, cur[2], acc[1][2], 0, 0, 0);
#pragma unroll
            for (int j = 0; j < 3; ++j) { cur[j] = nxt[j]; nxt[j] = tmp[j]; }
        }

        const int tb = chunk * 96 + wt * 48;
#pragma unroll
        for (int i = 0; i < 2; ++i) {
#pragma unroll
            for (int j = 0; j < 3; ++j) {
                int t = tb + j * 16 + c;
#pragma unroll
                for (int r = 0; r < 4; ++r) {
                    int m = wm * 32 + i * 16 + kq * 4 + r;
                    Ob[(size_t)m * T_ + t] = acc[i][j][r];
                }
            }
        }
    }
}

// ---------------------------------------------------------------------------
extern "C" void kernel_launch(void* const* d_in, const int* in_sizes, int n_in,
                              void* d_out, int out_size, void* d_ws, size_t ws_size,
                              hipStream_t stream) {
    const float* x = (const float*)d_in[0];
    const float* W1 = (const float*)d_in[1];
    const float* W2 = (const float*)d_in[2];
    const float* alpha = (const float*)d_in[3];
    float* out = (float*)d_out;

    char* ws = (char*)d_ws;
    float* Kt = (float*)ws;                      ws += (size_t)B_ * N_ * T_ * 4;
    float* KW1 = (float*)ws;                     ws += (size_t)B_ * T_ * R_ * 4;
    float* QW2 = (float*)ws;                     ws += (size_t)B_ * T_ * R_ * 4;
    unsigned short* Apk = (unsigned short*)ws;   ws += (size_t)B_ * TT_ * ST_ * 512 * 2;
    unsigned short* xbf = (unsigned short*)ws;
    size_t need = (size_t)(ws - (char*)d_ws) + (size_t)B_ * C_ * N_ * T_ * 2;
    const bool use_bf = (ws_size >= need);

    {
        int total = B_ * N_ * (T_ / 8);
        int blks = (total + 255) / 256;
        if (use_bf)
            k_reduce<1><<<blks, 256, 0, stream>>>(x, alpha, Kt, xbf);
        else
            k_reduce<0><<<blks, 256, 0, stream>>>(x, alpha, Kt, xbf);
    }
    k_proj<<<B_ * (T_ / 32), 256, 0, stream>>>(Kt, W1, W2, KW1, QW2);
    k_softmax<<<B_ * T_, 64, 0, stream>>>(KW1, QW2, Apk);
    {
        dim3 grid(M_ / 64, B_);  // 307 x 16
        if (use_bf)
            k_out<1><<<grid, 256, 0, stream>>>(nullptr, xbf, Apk, out);
        else
            k_out<0><<<grid, 256, 0, stream>>>(x, nullptr, Apk, out);
    }
}

// Round 7
// 310.286 us; speedup vs baseline: 1.9314x; 1.0513x over previous
//
#include <hip/hip_runtime.h>

#define B_ 16
#define C_ 64
#define N_ 307
#define T_ 288
#define R_ 10
#define M_ (C_ * N_)   // 19648 = 307*64
#define TT_ (T_ / 16)  // 18 t-tiles
#define ST_ (T_ / 32)  // 9 k-tiles

typedef __attribute__((ext_vector_type(8))) short bf16x8;
typedef __attribute__((ext_vector_type(4))) float f32x4;

__device__ __forceinline__ unsigned short f2bf(float f) {
    unsigned int u = __float_as_uint(f);
    unsigned int r = (u + 0x7fffu + ((u >> 16) & 1u)) >> 16;  // RNE
    return (unsigned short)r;
}
__device__ __forceinline__ unsigned int pack2(float a, float b) {
    return (unsigned int)f2bf(a) | ((unsigned int)f2bf(b) << 16);
}
__device__ __forceinline__ uint4 pack8v(f32x4 a, f32x4 b) {
    uint4 w;
    w.x = pack2(a.x, a.y); w.y = pack2(a.z, a.w);
    w.z = pack2(b.x, b.y); w.w = pack2(b.z, b.w);
    return w;
}

// ---------------------------------------------------------------------------
// Kernel 1: Kt[b,n,t] = sum_i alpha[i]*x[b,i,n,t] (coalesced writes), plus
// xbf = bf16(x) echo (stays L3-resident for k_out). x loads nontemporal
// (read-once) so they don't evict the xbf echo.
// ---------------------------------------------------------------------------
template <int WRITE_BF>
__global__ __launch_bounds__(256) void k_reduce(const float* __restrict__ x,
                                                const float* __restrict__ alpha,
                                                float* __restrict__ Kt,
                                                unsigned short* __restrict__ xbf) {
    __shared__ float a_s[C_];
    if (threadIdx.x < C_) a_s[threadIdx.x] = alpha[threadIdx.x];
    __syncthreads();
    const int T8 = T_ / 8;  // 36
    int idx = blockIdx.x * blockDim.x + threadIdx.x;
    const int total = B_ * N_ * T8;
    if (idx >= total) return;
    int t8 = idx % T8;
    int n = (idx / T8) % N_;
    int b = idx / (N_ * T8);
    const size_t chs = (size_t)N_ * T_;
    size_t base = ((size_t)(b * C_) * N_ + n) * T_ + t8 * 8;
    f32x4 s0 = {0.f, 0.f, 0.f, 0.f}, s1 = {0.f, 0.f, 0.f, 0.f};
#pragma unroll 4
    for (int i = 0; i < C_; ++i) {
        f32x4 v0 = __builtin_nontemporal_load((const f32x4*)(x + base + (size_t)i * chs));
        f32x4 v1 = __builtin_nontemporal_load((const f32x4*)(x + base + (size_t)i * chs + 4));
        float a = a_s[i];
        s0 += a * v0;
        s1 += a * v1;
        if (WRITE_BF) *(uint4*)(xbf + base + (size_t)i * chs) = pack8v(v0, v1);
    }
    size_t kb = ((size_t)b * N_ + n) * T_ + t8 * 8;
    *(f32x4*)(Kt + kb) = s0;
    *(f32x4*)(Kt + kb + 4) = s1;
}

// ---------------------------------------------------------------------------
// Kernel 2: KW1[b,t,r], QW2[b,t,r] from Kt[b,n,t]. 144 blocks, 8-way n-split.
// ---------------------------------------------------------------------------
#define PG 8
__global__ __launch_bounds__(256) void k_proj(const float* __restrict__ Kt,
                                              const float* __restrict__ W1,
                                              const float* __restrict__ W2,
                                              float* __restrict__ KW1,
                                              float* __restrict__ QW2) {
    __shared__ float Ws[2 * R_ * N_];
    __shared__ float part[PG][32][2 * R_];
    for (int e = threadIdx.x; e < R_ * N_; e += 256) {
        Ws[e] = W1[e];
        Ws[R_ * N_ + e] = W2[e];
    }
    __syncthreads();
    int b = blockIdx.x / (T_ / 32);
    int tc = blockIdx.x % (T_ / 32);
    int t0 = tc * 32;
    int g = threadIdx.x >> 5;
    int tl = threadIdx.x & 31;
    int n0 = g * 38 + (g < 3 ? g : 3);
    int n1 = n0 + 38 + (g < 3 ? 1 : 0);
    float a[2 * R_];
#pragma unroll
    for (int r = 0; r < 2 * R_; ++r) a[r] = 0.f;
    const float* kp = Kt + (size_t)b * N_ * T_ + t0 + tl;
    for (int n = n0; n < n1; ++n) {
        float kv = kp[(size_t)n * T_];
#pragma unroll
        for (int r = 0; r < R_; ++r) {
            a[r] += kv * Ws[r * N_ + n];
            a[R_ + r] += kv * Ws[R_ * N_ + r * N_ + n];
        }
    }
#pragma unroll
    for (int r = 0; r < 2 * R_; ++r) part[g][tl][r] = a[r];
    __syncthreads();
    for (int o = threadIdx.x; o < 32 * 2 * R_; o += 256) {
        int tl2 = o / (2 * R_);
        int rr = o % (2 * R_);
        float s = 0.f;
#pragma unroll
        for (int gg = 0; gg < PG; ++gg) s += part[gg][tl2][rr];
        int t = t0 + tl2;
        if (rr < R_) KW1[((size_t)b * T_ + t) * R_ + rr] = s;
        else         QW2[((size_t)b * T_ + t) * R_ + rr - R_] = s;
    }
}

// ---------------------------------------------------------------------------
// Kernel 3: scores -> softmax -> Apk in MFMA A-operand fragment layout:
//   Apk[((b*18 + tt)*9 + st)*512 + (tl + 16*q)*8 + e] = A[b][t=tt*16+tl][s=st*32+q*8+e]
// (lane l reads offset l*8: row=l&15 -> t, k=(l>>4)*8+e -> s). One wave/(b,t).
// ---------------------------------------------------------------------------
__global__ __launch_bounds__(64) void k_softmax(const float* __restrict__ KW1,
                                                const float* __restrict__ QW2,
                                                unsigned short* __restrict__ Apk) {
    __shared__ __align__(16) unsigned short sm[T_];
    int bt = blockIdx.x;
    int b = bt / T_;
    int t = bt % T_;
    int lane = threadIdx.x;
    float kw[R_];
#pragma unroll
    for (int r = 0; r < R_; ++r) kw[r] = KW1[bt * R_ + r];
    float sc[5];
    float mx = -1e30f;
#pragma unroll
    for (int j = 0; j < 5; ++j) {
        int s = lane + j * 64;
        float v = -1e30f;
        if (s < T_) {
            const float* q = QW2 + ((size_t)b * T_ + s) * R_;
            v = 0.f;
#pragma unroll
            for (int r = 0; r < R_; ++r) v += kw[r] * q[r];
        }
        sc[j] = v;
        mx = fmaxf(mx, v);
    }
#pragma unroll
    for (int off = 32; off > 0; off >>= 1) mx = fmaxf(mx, __shfl_xor(mx, off));
    float sum = 0.f;
#pragma unroll
    for (int j = 0; j < 5; ++j) {
        int s = lane + j * 64;
        float e = (s < T_) ? __expf(sc[j] - mx) : 0.f;
        sc[j] = e;
        sum += e;
    }
#pragma unroll
    for (int off = 32; off > 0; off >>= 1) sum += __shfl_xor(sum, off);
    float inv = 1.f / sum;
#pragma unroll
    for (int j = 0; j < 5; ++j) {
        int s = lane + j * 64;
        if (s < T_) sm[s] = f2bf(sc[j] * inv);
    }
    __syncthreads();
    if (lane < 36) {
        int st = lane >> 2, q = lane & 3;
        uint4 v = *(const uint4*)&sm[st * 32 + q * 8];
        int tt = t >> 4, tl = t & 15;
        size_t dst = ((((size_t)b * TT_ + tt) * ST_ + st) * 64 + tl + 16 * q) * 8;
        *(uint4*)(Apk + dst) = v;
    }
}

// ---------------------------------------------------------------------------
// Kernel 4: out[b,m,t] = sum_s A[b,t,s]*X[b,m,s], mfma_f32_16x16x32_bf16
// with ATTENTION as the A-operand and X as the B-operand:
//   D[row=t(local), col=m(local)]; lane holds 4 CONSECUTIVE t for one m
//   -> epilogue is coalesced f32x4 nontemporal stores (was 72 scalar dwords).
// X panel (64m x 288s) staged to LDS once; A fragments from Apk, one
// dwordx4/lane each, 3-step-deep register prefetch (static indices).
// ---------------------------------------------------------------------------
template <int XBF>
__global__ __launch_bounds__(256, 4) void k_out(const float* __restrict__ xf,
                                                const unsigned short* __restrict__ xb,
                                                const unsigned short* __restrict__ Apk,
                                                float* __restrict__ out) {
    const int m0 = blockIdx.x * 64;
    const int b = blockIdx.y;

    __shared__ __align__(16) unsigned short Xs[64][296];  // 37,888 B

    const int tid = threadIdx.x;
    const int lane = tid & 63;
    const int wid = tid >> 6;
    const int wm = wid & 1;   // m half (32 rows)
    const int wt = wid >> 1;  // t half (48 of each 96-chunk)
    const int c = lane & 15;
    const int kq = lane >> 4;

    // ---- stage X panel (64 x 288) once ----
    {
        const size_t Xg = ((size_t)b * M_ + m0) * T_;
#pragma unroll
        for (int u = 0; u < 9; ++u) {
            int e = tid + u * 256;
            int row = e / 36;
            int ch = e % 36;
            if (XBF) {
                *(uint4*)&Xs[row][ch * 8] = *(const uint4*)(xb + Xg + (size_t)row * T_ + ch * 8);
            } else {
                f32x4 v0 = *(const f32x4*)(xf + Xg + (size_t)row * T_ + ch * 8);
                f32x4 v1 = *(const f32x4*)(xf + Xg + (size_t)row * T_ + ch * 8 + 4);
                *(uint4*)&Xs[row][ch * 8] = pack8v(v0, v1);
            }
        }
    }
    __syncthreads();

    float* Ob = out + ((size_t)b * M_ + m0) * T_;

    for (int chunk = 0; chunk < 3; ++chunk) {
        const int tt0 = chunk * 6 + wt * 3;  // first of 3 t-tiles for this wave
        const unsigned short* bb[3];
#pragma unroll
        for (int j = 0; j < 3; ++j)
            bb[j] = Apk + (((size_t)b * TT_ + tt0 + j) * ST_) * 512 + (size_t)lane * 8;

        f32x4 acc[3][2];  // [t-frag][m-frag]
#pragma unroll
        for (int j = 0; j < 3; ++j)
#pragma unroll
            for (int i = 0; i < 2; ++i) acc[j][i] = (f32x4){0.f, 0.f, 0.f, 0.f};

        bf16x8 abuf[3][3];  // [k%3][t-frag], 3-deep prefetch
#pragma unroll
        for (int d = 0; d < 3; ++d)
#pragma unroll
            for (int j = 0; j < 3; ++j)
                abuf[d][j] = *(const bf16x8*)(bb[j] + (size_t)d * 512);

#pragma unroll
        for (int k = 0; k < 9; ++k) {
            bf16x8 x0 = *(const bf16x8*)&Xs[wm * 32 + c][k * 32 + kq * 8];
            bf16x8 x1 = *(const bf16x8*)&Xs[wm * 32 + 16 + c][k * 32 + kq * 8];
            acc[0][0] = __builtin_amdgcn_mfma_f32_16x16x32_bf16(abuf[k % 3][0], x0, acc[0][0], 0, 0, 0);
            acc[0][1] = __builtin_amdgcn_mfma_f32_16x16x32_bf16(abuf[k % 3][0], x1, acc[0][1], 0, 0, 0);
            acc[1][0] = __builtin_amdgcn_mfma_f32_16x16x32_bf16(abuf[k % 3][1], x0, acc[1][0], 0, 0, 0);
            acc[1][1] = __builtin_amdgcn_mfma_f32_16x16x32_bf16(abuf[k % 3][1], x1, acc[1][1], 0, 0, 0);
            acc[2][0] = __builtin_amdgcn_mfma_f32_16x16x32_bf16(abuf[k % 3][2], x0, acc[2][0], 0, 0, 0);
            acc[2][1] = __builtin_amdgcn_mfma_f32_16x16x32_bf16(abuf[k % 3][2], x1, acc[2][1], 0, 0, 0);
            if (k + 3 < 9) {
#pragma unroll
                for (int j = 0; j < 3; ++j)
                    abuf[k % 3][j] = *(const bf16x8*)(bb[j] + (size_t)(k + 3) * 512);
            }
        }

        const int tb = chunk * 96 + wt * 48;
#pragma unroll
        for (int j = 0; j < 3; ++j) {
            int t = tb + j * 16 + kq * 4;
#pragma unroll
            for (int i = 0; i < 2; ++i) {
                int m = wm * 32 + i * 16 + c;
                __builtin_nontemporal_store(acc[j][i], (f32x4*)&Ob[(size_t)m * T_ + t]);
            }
        }
    }
}

// ---------------------------------------------------------------------------
extern "C" void kernel_launch(void* const* d_in, const int* in_sizes, int n_in,
                              void* d_out, int out_size, void* d_ws, size_t ws_size,
                              hipStream_t stream) {
    const float* x = (const float*)d_in[0];
    const float* W1 = (const float*)d_in[1];
    const float* W2 = (const float*)d_in[2];
    const float* alpha = (const float*)d_in[3];
    float* out = (float*)d_out;

    char* ws = (char*)d_ws;
    float* Kt = (float*)ws;                      ws += (size_t)B_ * N_ * T_ * 4;
    float* KW1 = (float*)ws;                     ws += (size_t)B_ * T_ * R_ * 4;
    float* QW2 = (float*)ws;                     ws += (size_t)B_ * T_ * R_ * 4;
    unsigned short* Apk = (unsigned short*)ws;   ws += (size_t)B_ * TT_ * ST_ * 512 * 2;
    unsigned short* xbf = (unsigned short*)ws;
    size_t need = (size_t)(ws - (char*)d_ws) + (size_t)B_ * C_ * N_ * T_ * 2;
    const bool use_bf = (ws_size >= need);

    {
        int total = B_ * N_ * (T_ / 8);
        int blks = (total + 255) / 256;
        if (use_bf)
            k_reduce<1><<<blks, 256, 0, stream>>>(x, alpha, Kt, xbf);
        else
            k_reduce<0><<<blks, 256, 0, stream>>>(x, alpha, Kt, xbf);
    }
    k_proj<<<B_ * (T_ / 32), 256, 0, stream>>>(Kt, W1, W2, KW1, QW2);
    k_softmax<<<B_ * T_, 64, 0, stream>>>(KW1, QW2, Apk);
    {
        dim3 grid(M_ / 64, B_);  // 307 x 16
        if (use_bf)
            k_out<1><<<grid, 256, 0, stream>>>(nullptr, xbf, Apk, out);
        else
            k_out<0><<<grid, 256, 0, stream>>>(x, nullptr, Apk, out);
    }
}

// Round 9
// 238.335 us; speedup vs baseline: 2.5145x; 1.3019x over previous
//
#include <hip/hip_runtime.h>

#define B_ 16
#define C_ 64
#define N_ 307
#define T_ 288
#define R_ 10
#define M_ (C_ * N_)   // 19648 = 307*64
#define TT_ (T_ / 16)  // 18 t-tiles
#define ST_ (T_ / 32)  // 9 k-tiles

typedef __attribute__((ext_vector_type(8))) short bf16x8;
typedef __attribute__((ext_vector_type(4))) float f32x4;
typedef __attribute__((ext_vector_type(4))) unsigned int u32x4;

__device__ __forceinline__ unsigned short f2bf(float f) {
    unsigned int u = __float_as_uint(f);
    unsigned int r = (u + 0x7fffu + ((u >> 16) & 1u)) >> 16;  // RNE
    return (unsigned short)r;
}
__device__ __forceinline__ unsigned int pack2(float a, float b) {
    return (unsigned int)f2bf(a) | ((unsigned int)f2bf(b) << 16);
}
__device__ __forceinline__ u32x4 pack8v(f32x4 a, f32x4 b) {
    u32x4 w;
    w.x = pack2(a.x, a.y); w.y = pack2(a.z, a.w);
    w.z = pack2(b.x, b.y); w.w = pack2(b.z, b.w);
    return w;
}

// ---------------------------------------------------------------------------
// Kernel 1: Kt[b,n,t] = sum_i alpha[i]*x[b,i,n,t] (coalesced writes), plus
// xbf = bf16(x) echo (stays L3-resident for k_out). x loads nontemporal
// (read-once) so they don't evict the xbf echo.
// ---------------------------------------------------------------------------
template <int WRITE_BF>
__global__ __launch_bounds__(256) void k_reduce(const float* __restrict__ x,
                                                const float* __restrict__ alpha,
                                                float* __restrict__ Kt,
                                                unsigned short* __restrict__ xbf) {
    __shared__ float a_s[C_];
    if (threadIdx.x < C_) a_s[threadIdx.x] = alpha[threadIdx.x];
    __syncthreads();
    const int T8 = T_ / 8;  // 36
    int idx = blockIdx.x * blockDim.x + threadIdx.x;
    const int total = B_ * N_ * T8;
    if (idx >= total) return;
    int t8 = idx % T8;
    int n = (idx / T8) % N_;
    int b = idx / (N_ * T8);
    const size_t chs = (size_t)N_ * T_;
    size_t base = ((size_t)(b * C_) * N_ + n) * T_ + t8 * 8;
    f32x4 s0 = {0.f, 0.f, 0.f, 0.f}, s1 = {0.f, 0.f, 0.f, 0.f};
#pragma unroll 4
    for (int i = 0; i < C_; ++i) {
        f32x4 v0 = __builtin_nontemporal_load((const f32x4*)(x + base + (size_t)i * chs));
        f32x4 v1 = __builtin_nontemporal_load((const f32x4*)(x + base + (size_t)i * chs + 4));
        float a = a_s[i];
        s0 += a * v0;
        s1 += a * v1;
        if (WRITE_BF) *(u32x4*)(xbf + base + (size_t)i * chs) = pack8v(v0, v1);
    }
    size_t kb = ((size_t)b * N_ + n) * T_ + t8 * 8;
    *(f32x4*)(Kt + kb) = s0;
    *(f32x4*)(Kt + kb + 4) = s1;
}

// ---------------------------------------------------------------------------
// Kernel 2: KW1[b,t,r], QW2[b,t,r] from Kt[b,n,t]. 144 blocks, 8-way n-split.
// ---------------------------------------------------------------------------
#define PG 8
__global__ __launch_bounds__(256) void k_proj(const float* __restrict__ Kt,
                                              const float* __restrict__ W1,
                                              const float* __restrict__ W2,
                                              float* __restrict__ KW1,
                                              float* __restrict__ QW2) {
    __shared__ float Ws[2 * R_ * N_];
    __shared__ float part[PG][32][2 * R_];
    for (int e = threadIdx.x; e < R_ * N_; e += 256) {
        Ws[e] = W1[e];
        Ws[R_ * N_ + e] = W2[e];
    }
    __syncthreads();
    int b = blockIdx.x / (T_ / 32);
    int tc = blockIdx.x % (T_ / 32);
    int t0 = tc * 32;
    int g = threadIdx.x >> 5;
    int tl = threadIdx.x & 31;
    int n0 = g * 38 + (g < 3 ? g : 3);
    int n1 = n0 + 38 + (g < 3 ? 1 : 0);
    float a[2 * R_];
#pragma unroll
    for (int r = 0; r < 2 * R_; ++r) a[r] = 0.f;
    const float* kp = Kt + (size_t)b * N_ * T_ + t0 + tl;
    for (int n = n0; n < n1; ++n) {
        float kv = kp[(size_t)n * T_];
#pragma unroll
        for (int r = 0; r < R_; ++r) {
            a[r] += kv * Ws[r * N_ + n];
            a[R_ + r] += kv * Ws[R_ * N_ + r * N_ + n];
        }
    }
#pragma unroll
    for (int r = 0; r < 2 * R_; ++r) part[g][tl][r] = a[r];
    __syncthreads();
    for (int o = threadIdx.x; o < 32 * 2 * R_; o += 256) {
        int tl2 = o / (2 * R_);
        int rr = o % (2 * R_);
        float s = 0.f;
#pragma unroll
        for (int gg = 0; gg < PG; ++gg) s += part[gg][tl2][rr];
        int t = t0 + tl2;
        if (rr < R_) KW1[((size_t)b * T_ + t) * R_ + rr] = s;
        else         QW2[((size_t)b * T_ + t) * R_ + rr - R_] = s;
    }
}

// ---------------------------------------------------------------------------
// Kernel 3: scores -> softmax -> Apk in MFMA A-operand fragment layout:
//   Apk[((b*18 + tt)*9 + st)*512 + (tl + 16*q)*8 + e] = A[b][t=tt*16+tl][s=st*32+q*8+e]
// (lane l reads offset l*8: row=l&15 -> t, k=(l>>4)*8+e -> s). One wave/(b,t).
// ---------------------------------------------------------------------------
__global__ __launch_bounds__(64) void k_softmax(const float* __restrict__ KW1,
                                                const float* __restrict__ QW2,
                                                unsigned short* __restrict__ Apk) {
    __shared__ __align__(16) unsigned short sm[T_];
    int bt = blockIdx.x;
    int b = bt / T_;
    int t = bt % T_;
    int lane = threadIdx.x;
    float kw[R_];
#pragma unroll
    for (int r = 0; r < R_; ++r) kw[r] = KW1[bt * R_ + r];
    float sc[5];
    float mx = -1e30f;
#pragma unroll
    for (int j = 0; j < 5; ++j) {
        int s = lane + j * 64;
        float v = -1e30f;
        if (s < T_) {
            const float* q = QW2 + ((size_t)b * T_ + s) * R_;
            v = 0.f;
#pragma unroll
            for (int r = 0; r < R_; ++r) v += kw[r] * q[r];
        }
        sc[j] = v;
        mx = fmaxf(mx, v);
    }
#pragma unroll
    for (int off = 32; off > 0; off >>= 1) mx = fmaxf(mx, __shfl_xor(mx, off));
    float sum = 0.f;
#pragma unroll
    for (int j = 0; j < 5; ++j) {
        int s = lane + j * 64;
        float e = (s < T_) ? __expf(sc[j] - mx) : 0.f;
        sc[j] = e;
        sum += e;
    }
#pragma unroll
    for (int off = 32; off > 0; off >>= 1) sum += __shfl_xor(sum, off);
    float inv = 1.f / sum;
#pragma unroll
    for (int j = 0; j < 5; ++j) {
        int s = lane + j * 64;
        if (s < T_) sm[s] = f2bf(sc[j] * inv);
    }
    __syncthreads();
    if (lane < 36) {
        int st = lane >> 2, q = lane & 3;
        u32x4 v = *(const u32x4*)&sm[st * 32 + q * 8];
        int tt = t >> 4, tl = t & 15;
        size_t dst = ((((size_t)b * TT_ + tt) * ST_ + st) * 64 + tl + 16 * q) * 8;
        *(u32x4*)(Apk + dst) = v;
    }
}

// ---------------------------------------------------------------------------
// Kernel 4: out[b,m,t] = sum_s A[b,t,s]*X[b,m,s], mfma_f32_16x16x32_bf16,
// attention as A-operand (coalesced f32x4 store epilogue).
// X staging loads NONTEMPORAL (read-once; no L2 allocation) so the packed-A
// working set (2.6 MB total) stays L2-resident and the per-step A-fragment
// loads hit L2 (~200cy, covered by the 3-deep prefetch) instead of L3.
// s_setprio around MFMA cluster; prefetch issued before MFMAs, committed after.
// ---------------------------------------------------------------------------
template <int XBF>
__global__ __launch_bounds__(256, 4) void k_out(const float* __restrict__ xf,
                                                const unsigned short* __restrict__ xb,
                                                const unsigned short* __restrict__ Apk,
                                                float* __restrict__ out) {
    const int m0 = blockIdx.x * 64;
    const int b = blockIdx.y;

    __shared__ __align__(16) unsigned short Xs[64][296];  // 37,888 B

    const int tid = threadIdx.x;
    const int lane = tid & 63;
    const int wid = tid >> 6;
    const int wm = wid & 1;   // m half (32 rows)
    const int wt = wid >> 1;  // t half (48 of each 96-chunk)
    const int c = lane & 15;
    const int kq = lane >> 4;

    // ---- stage X panel (64 x 288) once; nontemporal reads ----
    {
        const size_t Xg = ((size_t)b * M_ + m0) * T_;
#pragma unroll
        for (int u = 0; u < 9; ++u) {
            int e = tid + u * 256;
            int row = e / 36;
            int ch = e % 36;
            if (XBF) {
                u32x4 v = __builtin_nontemporal_load((const u32x4*)(xb + Xg + (size_t)row * T_ + ch * 8));
                *(u32x4*)&Xs[row][ch * 8] = v;
            } else {
                f32x4 v0 = __builtin_nontemporal_load((const f32x4*)(xf + Xg + (size_t)row * T_ + ch * 8));
                f32x4 v1 = __builtin_nontemporal_load((const f32x4*)(xf + Xg + (size_t)row * T_ + ch * 8 + 4));
                *(u32x4*)&Xs[row][ch * 8] = pack8v(v0, v1);
            }
        }
    }
    __syncthreads();

    float* Ob = out + ((size_t)b * M_ + m0) * T_;

    for (int chunk = 0; chunk < 3; ++chunk) {
        const int tt0 = chunk * 6 + wt * 3;  // first of 3 t-tiles for this wave
        const unsigned short* bb[3];
#pragma unroll
        for (int j = 0; j < 3; ++j)
            bb[j] = Apk + (((size_t)b * TT_ + tt0 + j) * ST_) * 512 + (size_t)lane * 8;

        f32x4 acc[3][2];  // [t-frag][m-frag]
#pragma unroll
        for (int j = 0; j < 3; ++j)
#pragma unroll
            for (int i = 0; i < 2; ++i) acc[j][i] = (f32x4){0.f, 0.f, 0.f, 0.f};

        bf16x8 abuf[3][3];  // [k%3][t-frag], 3-deep prefetch
#pragma unroll
        for (int d = 0; d < 3; ++d)
#pragma unroll
            for (int j = 0; j < 3; ++j)
                abuf[d][j] = *(const bf16x8*)(bb[j] + (size_t)d * 512);

#pragma unroll
        for (int k = 0; k < 9; ++k) {
            // issue next prefetch BEFORE the MFMA cluster (overlaps compute)
            bf16x8 tmp[3];
            if (k + 3 < 9) {
#pragma unroll
                for (int j = 0; j < 3; ++j)
                    tmp[j] = *(const bf16x8*)(bb[j] + (size_t)(k + 3) * 512);
            }
            bf16x8 x0 = *(const bf16x8*)&Xs[wm * 32 + c][k * 32 + kq * 8];
            bf16x8 x1 = *(const bf16x8*)&Xs[wm * 32 + 16 + c][k * 32 + kq * 8];
            __builtin_amdgcn_s_setprio(1);
            acc[0][0] = __builtin_amdgcn_mfma_f32_16x16x32_bf16(abuf[k % 3][0], x0, acc[0][0], 0, 0, 0);
            acc[0][1] = __builtin_amdgcn_mfma_f32_16x16x32_bf16(abuf[k % 3][0], x1, acc[0][1], 0, 0, 0);
            acc[1][0] = __builtin_amdgcn_mfma_f32_16x16x32_bf16(abuf[k % 3][1], x0, acc[1][0], 0, 0, 0);
            acc[1][1] = __builtin_amdgcn_mfma_f32_16x16x32_bf16(abuf[k % 3][1], x1, acc[1][1], 0, 0, 0);
            acc[2][0] = __builtin_amdgcn_mfma_f32_16x16x32_bf16(abuf[k % 3][2], x0, acc[2][0], 0, 0, 0);
            acc[2][1] = __builtin_amdgcn_mfma_f32_16x16x32_bf16(abuf[k % 3][2], x1, acc[2][1], 0, 0, 0);
            __builtin_amdgcn_s_setprio(0);
            if (k + 3 < 9) {
#pragma unroll
                for (int j = 0; j < 3; ++j) abuf[k % 3][j] = tmp[j];
            }
        }

        const int tb = chunk * 96 + wt * 48;
#pragma unroll
        for (int j = 0; j < 3; ++j) {
            int t = tb + j * 16 + kq * 4;
#pragma unroll
            for (int i = 0; i < 2; ++i) {
                int m = wm * 32 + i * 16 + c;
                __builtin_nontemporal_store(acc[j][i], (f32x4*)&Ob[(size_t)m * T_ + t]);
            }
        }
    }
}

// ---------------------------------------------------------------------------
extern "C" void kernel_launch(void* const* d_in, const int* in_sizes, int n_in,
                              void* d_out, int out_size, void* d_ws, size_t ws_size,
                              hipStream_t stream) {
    const float* x = (const float*)d_in[0];
    const float* W1 = (const float*)d_in[1];
    const float* W2 = (const float*)d_in[2];
    const float* alpha = (const float*)d_in[3];
    float* out = (float*)d_out;

    char* ws = (char*)d_ws;
    float* Kt = (float*)ws;                      ws += (size_t)B_ * N_ * T_ * 4;
    float* KW1 = (float*)ws;                     ws += (size_t)B_ * T_ * R_ * 4;
    float* QW2 = (float*)ws;                     ws += (size_t)B_ * T_ * R_ * 4;
    unsigned short* Apk = (unsigned short*)ws;   ws += (size_t)B_ * TT_ * ST_ * 512 * 2;
    unsigned short* xbf = (unsigned short*)ws;
    size_t need = (size_t)(ws - (char*)d_ws) + (size_t)B_ * C_ * N_ * T_ * 2;
    const bool use_bf = (ws_size >= need);

    {
        int total = B_ * N_ * (T_ / 8);
        int blks = (total + 255) / 256;
        if (use_bf)
            k_reduce<1><<<blks, 256, 0, stream>>>(x, alpha, Kt, xbf);
        else
            k_reduce<0><<<blks, 256, 0, stream>>>(x, alpha, Kt, xbf);
    }
    k_proj<<<B_ * (T_ / 32), 256, 0, stream>>>(Kt, W1, W2, KW1, QW2);
    k_softmax<<<B_ * T_, 64, 0, stream>>>(KW1, QW2, Apk);
    {
        dim3 grid(M_ / 64, B_);  // 307 x 16
        if (use_bf)
            k_out<1><<<grid, 256, 0, stream>>>(nullptr, xbf, Apk, out);
        else
            k_out<0><<<grid, 256, 0, stream>>>(x, nullptr, Apk, out);
    }
}

// Round 10
// 235.977 us; speedup vs baseline: 2.5396x; 1.0100x over previous
//
#include <hip/hip_runtime.h>

#define B_ 16
#define C_ 64
#define N_ 307
#define T_ 288
#define R_ 10
#define M_ (C_ * N_)   // 19648 = 307*64
#define TT_ (T_ / 16)  // 18 t-tiles
#define ST_ (T_ / 32)  // 9 k-tiles

typedef __attribute__((ext_vector_type(8))) short bf16x8;
typedef __attribute__((ext_vector_type(4))) float f32x4;
typedef __attribute__((ext_vector_type(4))) unsigned int u32x4;

__device__ __forceinline__ unsigned short f2bf(float f) {
    unsigned int u = __float_as_uint(f);
    unsigned int r = (u + 0x7fffu + ((u >> 16) & 1u)) >> 16;  // RNE
    return (unsigned short)r;
}
__device__ __forceinline__ unsigned int pack2(float a, float b) {
    return (unsigned int)f2bf(a) | ((unsigned int)f2bf(b) << 16);
}
__device__ __forceinline__ u32x4 pack8v(f32x4 a, f32x4 b) {
    u32x4 w;
    w.x = pack2(a.x, a.y); w.y = pack2(a.z, a.w);
    w.z = pack2(b.x, b.y); w.w = pack2(b.z, b.w);
    return w;
}

// ---------------------------------------------------------------------------
// Kernel 1: Kt[b,n,t] = sum_i alpha[i]*x[b,i,n,t] (coalesced writes), plus
// xbf = bf16(x) echo (stays L3-resident for k_out). x loads nontemporal.
// unroll 8: ~16 loads in flight/wave (grid gives only ~11 waves/CU, so
// per-wave ILP carries the latency hiding).
// ---------------------------------------------------------------------------
template <int WRITE_BF>
__global__ __launch_bounds__(256) void k_reduce(const float* __restrict__ x,
                                                const float* __restrict__ alpha,
                                                float* __restrict__ Kt,
                                                unsigned short* __restrict__ xbf) {
    __shared__ float a_s[C_];
    if (threadIdx.x < C_) a_s[threadIdx.x] = alpha[threadIdx.x];
    __syncthreads();
    const int T8 = T_ / 8;  // 36
    int idx = blockIdx.x * blockDim.x + threadIdx.x;
    const int total = B_ * N_ * T8;
    if (idx >= total) return;
    int t8 = idx % T8;
    int n = (idx / T8) % N_;
    int b = idx / (N_ * T8);
    const size_t chs = (size_t)N_ * T_;
    size_t base = ((size_t)(b * C_) * N_ + n) * T_ + t8 * 8;
    f32x4 s0 = {0.f, 0.f, 0.f, 0.f}, s1 = {0.f, 0.f, 0.f, 0.f};
#pragma unroll 8
    for (int i = 0; i < C_; ++i) {
        f32x4 v0 = __builtin_nontemporal_load((const f32x4*)(x + base + (size_t)i * chs));
        f32x4 v1 = __builtin_nontemporal_load((const f32x4*)(x + base + (size_t)i * chs + 4));
        float a = a_s[i];
        s0 += a * v0;
        s1 += a * v1;
        if (WRITE_BF) *(u32x4*)(xbf + base + (size_t)i * chs) = pack8v(v0, v1);
    }
    size_t kb = ((size_t)b * N_ + n) * T_ + t8 * 8;
    *(f32x4*)(Kt + kb) = s0;
    *(f32x4*)(Kt + kb + 4) = s1;
}

// ---------------------------------------------------------------------------
// Kernel 2: KW1[b,t,r], QW2[b,t,r] from Kt[b,n,t]. 144 blocks, 8-way n-split.
// ---------------------------------------------------------------------------
#define PG 8
__global__ __launch_bounds__(256) void k_proj(const float* __restrict__ Kt,
                                              const float* __restrict__ W1,
                                              const float* __restrict__ W2,
                                              float* __restrict__ KW1,
                                              float* __restrict__ QW2) {
    __shared__ float Ws[2 * R_ * N_];
    __shared__ float part[PG][32][2 * R_];
    for (int e = threadIdx.x; e < R_ * N_; e += 256) {
        Ws[e] = W1[e];
        Ws[R_ * N_ + e] = W2[e];
    }
    __syncthreads();
    int b = blockIdx.x / (T_ / 32);
    int tc = blockIdx.x % (T_ / 32);
    int t0 = tc * 32;
    int g = threadIdx.x >> 5;
    int tl = threadIdx.x & 31;
    int n0 = g * 38 + (g < 3 ? g : 3);
    int n1 = n0 + 38 + (g < 3 ? 1 : 0);
    float a[2 * R_];
#pragma unroll
    for (int r = 0; r < 2 * R_; ++r) a[r] = 0.f;
    const float* kp = Kt + (size_t)b * N_ * T_ + t0 + tl;
    for (int n = n0; n < n1; ++n) {
        float kv = kp[(size_t)n * T_];
#pragma unroll
        for (int r = 0; r < R_; ++r) {
            a[r] += kv * Ws[r * N_ + n];
            a[R_ + r] += kv * Ws[R_ * N_ + r * N_ + n];
        }
    }
#pragma unroll
    for (int r = 0; r < 2 * R_; ++r) part[g][tl][r] = a[r];
    __syncthreads();
    for (int o = threadIdx.x; o < 32 * 2 * R_; o += 256) {
        int tl2 = o / (2 * R_);
        int rr = o % (2 * R_);
        float s = 0.f;
#pragma unroll
        for (int gg = 0; gg < PG; ++gg) s += part[gg][tl2][rr];
        int t = t0 + tl2;
        if (rr < R_) KW1[((size_t)b * T_ + t) * R_ + rr] = s;
        else         QW2[((size_t)b * T_ + t) * R_ + rr - R_] = s;
    }
}

// ---------------------------------------------------------------------------
// Kernel 3: scores -> softmax -> Apk in MFMA A-operand fragment layout:
//   Apk[((b*18 + tt)*9 + st)*512 + (tl + 16*q)*8 + e] = A[b][t=tt*16+tl][s=st*32+q*8+e]
// ---------------------------------------------------------------------------
__global__ __launch_bounds__(64) void k_softmax(const float* __restrict__ KW1,
                                                const float* __restrict__ QW2,
                                                unsigned short* __restrict__ Apk) {
    __shared__ __align__(16) unsigned short sm[T_];
    int bt = blockIdx.x;
    int b = bt / T_;
    int t = bt % T_;
    int lane = threadIdx.x;
    float kw[R_];
#pragma unroll
    for (int r = 0; r < R_; ++r) kw[r] = KW1[bt * R_ + r];
    float sc[5];
    float mx = -1e30f;
#pragma unroll
    for (int j = 0; j < 5; ++j) {
        int s = lane + j * 64;
        float v = -1e30f;
        if (s < T_) {
            const float* q = QW2 + ((size_t)b * T_ + s) * R_;
            v = 0.f;
#pragma unroll
            for (int r = 0; r < R_; ++r) v += kw[r] * q[r];
        }
        sc[j] = v;
        mx = fmaxf(mx, v);
    }
#pragma unroll
    for (int off = 32; off > 0; off >>= 1) mx = fmaxf(mx, __shfl_xor(mx, off));
    float sum = 0.f;
#pragma unroll
    for (int j = 0; j < 5; ++j) {
        int s = lane + j * 64;
        float e = (s < T_) ? __expf(sc[j] - mx) : 0.f;
        sc[j] = e;
        sum += e;
    }
#pragma unroll
    for (int off = 32; off > 0; off >>= 1) sum += __shfl_xor(sum, off);
    float inv = 1.f / sum;
#pragma unroll
    for (int j = 0; j < 5; ++j) {
        int s = lane + j * 64;
        if (s < T_) sm[s] = f2bf(sc[j] * inv);
    }
    __syncthreads();
    if (lane < 36) {
        int st = lane >> 2, q = lane & 3;
        u32x4 v = *(const u32x4*)&sm[st * 32 + q * 8];
        int tt = t >> 4, tl = t & 15;
        size_t dst = ((((size_t)b * TT_ + tt) * ST_ + st) * 64 + tl + 16 * q) * 8;
        *(u32x4*)(Apk + dst) = v;
    }
}

// ---------------------------------------------------------------------------
// Kernel 4: out[b,m,t] = sum_s A[b,t,s]*X[b,m,s], mfma_f32_16x16x32_bf16,
// attention as A-operand. X panel staged to LDS once (NT reads). Main loop
// FLATTENED: 27 iterations (3 t-chunks x 9 k-steps) fully unrolled, with a
// rolling 4-deep A-fragment prefetch (static it%4 indices -> registers) that
// crosses chunk boundaries, so ~120-190cy of lookahead covers L2 latency at
// every step, including chunk starts. Fragment addresses = one per-lane base
// + compile-time constant offsets. Coalesced f32x4 NT store epilogue.
// ---------------------------------------------------------------------------
template <int XBF>
__global__ __launch_bounds__(256, 4) void k_out(const float* __restrict__ xf,
                                                const unsigned short* __restrict__ xb,
                                                const unsigned short* __restrict__ Apk,
                                                float* __restrict__ out) {
    const int m0 = blockIdx.x * 64;
    const int b = blockIdx.y;

    __shared__ __align__(16) unsigned short Xs[64][296];  // 37,888 B

    const int tid = threadIdx.x;
    const int lane = tid & 63;
    const int wid = tid >> 6;
    const int wm = wid & 1;   // m half (32 rows)
    const int wt = wid >> 1;  // t half (48 of each 96-chunk)
    const int c = lane & 15;
    const int kq = lane >> 4;

    // ---- stage X panel (64 x 288) once; nontemporal reads ----
    {
        const size_t Xg = ((size_t)b * M_ + m0) * T_;
#pragma unroll
        for (int u = 0; u < 9; ++u) {
            int e = tid + u * 256;
            int row = e / 36;
            int ch = e % 36;
            if (XBF) {
                u32x4 v = __builtin_nontemporal_load((const u32x4*)(xb + Xg + (size_t)row * T_ + ch * 8));
                *(u32x4*)&Xs[row][ch * 8] = v;
            } else {
                f32x4 v0 = __builtin_nontemporal_load((const f32x4*)(xf + Xg + (size_t)row * T_ + ch * 8));
                f32x4 v1 = __builtin_nontemporal_load((const f32x4*)(xf + Xg + (size_t)row * T_ + ch * 8 + 4));
                *(u32x4*)&Xs[row][ch * 8] = pack8v(v0, v1);
            }
        }
    }
    __syncthreads();

    float* Ob = out + ((size_t)b * M_ + m0) * T_;
    // fragment (it, j):  Abase + ((it/9)*6 + j)*ST_*512 + (it%9)*512
    const unsigned short* Abase =
        Apk + (((size_t)b * TT_ + wt * 3) * ST_) * 512 + (size_t)lane * 8;

    f32x4 acc[3][2];      // [t-frag][m-frag] for the CURRENT chunk
    bf16x8 abuf[4][3];    // rolling 4-deep prefetch

#pragma unroll
    for (int d = 0; d < 4; ++d)
#pragma unroll
        for (int j = 0; j < 3; ++j)
            abuf[d][j] = *(const bf16x8*)(Abase + ((size_t)(d / 9) * 6 + j) * (ST_ * 512) + (size_t)(d % 9) * 512);

#pragma unroll
    for (int it = 0; it < 27; ++it) {
        const int k = it % 9;
        const int chunk = it / 9;
        if (k == 0) {
#pragma unroll
            for (int j = 0; j < 3; ++j)
#pragma unroll
                for (int i = 0; i < 2; ++i) acc[j][i] = (f32x4){0.f, 0.f, 0.f, 0.f};
        }
        // issue prefetch for it+4 BEFORE the MFMA cluster
        bf16x8 tmp[3];
        if (it + 4 < 27) {
            const int nit = it + 4;
#pragma unroll
            for (int j = 0; j < 3; ++j)
                tmp[j] = *(const bf16x8*)(Abase + ((size_t)(nit / 9) * 6 + j) * (ST_ * 512) + (size_t)(nit % 9) * 512);
        }
        bf16x8 x0 = *(const bf16x8*)&Xs[wm * 32 + c][k * 32 + kq * 8];
        bf16x8 x1 = *(const bf16x8*)&Xs[wm * 32 + 16 + c][k * 32 + kq * 8];
        __builtin_amdgcn_s_setprio(1);
        acc[0][0] = __builtin_amdgcn_mfma_f32_16x16x32_bf16(abuf[it % 4][0], x0, acc[0][0], 0, 0, 0);
        acc[0][1] = __builtin_amdgcn_mfma_f32_16x16x32_bf16(abuf[it % 4][0], x1, acc[0][1], 0, 0, 0);
        acc[1][0] = __builtin_amdgcn_mfma_f32_16x16x32_bf16(abuf[it % 4][1], x0, acc[1][0], 0, 0, 0);
        acc[1][1] = __builtin_amdgcn_mfma_f32_16x16x32_bf16(abuf[it % 4][1], x1, acc[1][1], 0, 0, 0);
        acc[2][0] = __builtin_amdgcn_mfma_f32_16x16x32_bf16(abuf[it % 4][2], x0, acc[2][0], 0, 0, 0);
        acc[2][1] = __builtin_amdgcn_mfma_f32_16x16x32_bf16(abuf[it % 4][2], x1, acc[2][1], 0, 0, 0);
        __builtin_amdgcn_s_setprio(0);
        if (it + 4 < 27) {
#pragma unroll
            for (int j = 0; j < 3; ++j) abuf[it % 4][j] = tmp[j];
        }
        if (k == 8) {
            const int tb = chunk * 96 + wt * 48;
#pragma unroll
            for (int j = 0; j < 3; ++j) {
                int t = tb + j * 16 + kq * 4;
#pragma unroll
                for (int i = 0; i < 2; ++i) {
                    int m = wm * 32 + i * 16 + c;
                    __builtin_nontemporal_store(acc[j][i], (f32x4*)&Ob[(size_t)m * T_ + t]);
                }
            }
        }
    }
}

// ---------------------------------------------------------------------------
extern "C" void kernel_launch(void* const* d_in, const int* in_sizes, int n_in,
                              void* d_out, int out_size, void* d_ws, size_t ws_size,
                              hipStream_t stream) {
    const float* x = (const float*)d_in[0];
    const float* W1 = (const float*)d_in[1];
    const float* W2 = (const float*)d_in[2];
    const float* alpha = (const float*)d_in[3];
    float* out = (float*)d_out;

    char* ws = (char*)d_ws;
    float* Kt = (float*)ws;                      ws += (size_t)B_ * N_ * T_ * 4;
    float* KW1 = (float*)ws;                     ws += (size_t)B_ * T_ * R_ * 4;
    float* QW2 = (float*)ws;                     ws += (size_t)B_ * T_ * R_ * 4;
    unsigned short* Apk = (unsigned short*)ws;   ws += (size_t)B_ * TT_ * ST_ * 512 * 2;
    unsigned short* xbf = (unsigned short*)ws;
    size_t need = (size_t)(ws - (char*)d_ws) + (size_t)B_ * C_ * N_ * T_ * 2;
    const bool use_bf = (ws_size >= need);

    {
        int total = B_ * N_ * (T_ / 8);
        int blks = (total + 255) / 256;
        if (use_bf)
            k_reduce<1><<<blks, 256, 0, stream>>>(x, alpha, Kt, xbf);
        else
            k_reduce<0><<<blks, 256, 0, stream>>>(x, alpha, Kt, xbf);
    }
    k_proj<<<B_ * (T_ / 32), 256, 0, stream>>>(Kt, W1, W2, KW1, QW2);
    k_softmax<<<B_ * T_, 64, 0, stream>>>(KW1, QW2, Apk);
    {
        dim3 grid(M_ / 64, B_);  // 307 x 16
        if (use_bf)
            k_out<1><<<grid, 256, 0, stream>>>(nullptr, xbf, Apk, out);
        else
            k_out<0><<<grid, 256, 0, stream>>>(x, nullptr, Apk, out);
    }
}

// Round 11
// 234.278 us; speedup vs baseline: 2.5580x; 1.0073x over previous
//
#include <hip/hip_runtime.h>

#define B_ 16
#define C_ 64
#define N_ 307
#define T_ 288
#define R_ 10
#define M_ (C_ * N_)   // 19648 = 307*64
#define TT_ (T_ / 16)  // 18 t-tiles
#define ST_ (T_ / 32)  // 9 k-tiles

typedef __attribute__((ext_vector_type(8))) short bf16x8;
typedef __attribute__((ext_vector_type(4))) float f32x4;
typedef __attribute__((ext_vector_type(4))) unsigned int u32x4;
typedef __attribute__((ext_vector_type(2))) unsigned int u32x2;

__device__ __forceinline__ unsigned short f2bf(float f) {
    unsigned int u = __float_as_uint(f);
    unsigned int r = (u + 0x7fffu + ((u >> 16) & 1u)) >> 16;  // RNE
    return (unsigned short)r;
}
__device__ __forceinline__ unsigned int pack2(float a, float b) {
    return (unsigned int)f2bf(a) | ((unsigned int)f2bf(b) << 16);
}
__device__ __forceinline__ u32x4 pack8v(f32x4 a, f32x4 b) {
    u32x4 w;
    w.x = pack2(a.x, a.y); w.y = pack2(a.z, a.w);
    w.z = pack2(b.x, b.y); w.w = pack2(b.z, b.w);
    return w;
}
// HW packed f32->bf16 (RNE), one VALU op for two elements (guide m240 recipe)
__device__ __forceinline__ unsigned int cvtpk2(float lo, float hi) {
    unsigned int r;
    asm("v_cvt_pk_bf16_f32 %0, %1, %2" : "=v"(r) : "v"(lo), "v"(hi));
    return r;
}

// ---------------------------------------------------------------------------
// Kernel 1: Kt[b,n,t] = sum_i alpha[i]*x[b,i,n,t] (coalesced writes), plus
// xbf = bf16(x) echo (stays L3-resident for k_out). x loads nontemporal.
// t4 granularity: 1382 blocks (~22 waves/CU) for TLP; v_cvt_pk_bf16_f32
// packing (2 ops / 8B) instead of 16 VALU ops of bit-twiddled RNE.
// ---------------------------------------------------------------------------
template <int WRITE_BF>
__global__ __launch_bounds__(256) void k_reduce(const float* __restrict__ x,
                                                const float* __restrict__ alpha,
                                                float* __restrict__ Kt,
                                                unsigned short* __restrict__ xbf) {
    __shared__ float a_s[C_];
    if (threadIdx.x < C_) a_s[threadIdx.x] = alpha[threadIdx.x];
    __syncthreads();
    const int T4 = T_ / 4;  // 72
    int idx = blockIdx.x * blockDim.x + threadIdx.x;
    const int total = B_ * N_ * T4;
    if (idx >= total) return;
    int t4 = idx % T4;
    int n = (idx / T4) % N_;
    int b = idx / (N_ * T4);
    const size_t chs = (size_t)N_ * T_;
    size_t base = ((size_t)(b * C_) * N_ + n) * T_ + t4 * 4;
    f32x4 s = {0.f, 0.f, 0.f, 0.f};
#pragma unroll 8
    for (int i = 0; i < C_; ++i) {
        f32x4 v = __builtin_nontemporal_load((const f32x4*)(x + base + (size_t)i * chs));
        s += a_s[i] * v;
        if (WRITE_BF) {
            u32x2 w;
            w.x = cvtpk2(v.x, v.y);
            w.y = cvtpk2(v.z, v.w);
            *(u32x2*)(xbf + base + (size_t)i * chs) = w;
        }
    }
    *(f32x4*)(Kt + ((size_t)b * N_ + n) * T_ + t4 * 4) = s;
}

// ---------------------------------------------------------------------------
// Kernel 2: KW1[b,t,r], QW2[b,t,r] from Kt[b,n,t]. 144 blocks, 8-way n-split.
// ---------------------------------------------------------------------------
#define PG 8
__global__ __launch_bounds__(256) void k_proj(const float* __restrict__ Kt,
                                              const float* __restrict__ W1,
                                              const float* __restrict__ W2,
                                              float* __restrict__ KW1,
                                              float* __restrict__ QW2) {
    __shared__ float Ws[2 * R_ * N_];
    __shared__ float part[PG][32][2 * R_];
    for (int e = threadIdx.x; e < R_ * N_; e += 256) {
        Ws[e] = W1[e];
        Ws[R_ * N_ + e] = W2[e];
    }
    __syncthreads();
    int b = blockIdx.x / (T_ / 32);
    int tc = blockIdx.x % (T_ / 32);
    int t0 = tc * 32;
    int g = threadIdx.x >> 5;
    int tl = threadIdx.x & 31;
    int n0 = g * 38 + (g < 3 ? g : 3);
    int n1 = n0 + 38 + (g < 3 ? 1 : 0);
    float a[2 * R_];
#pragma unroll
    for (int r = 0; r < 2 * R_; ++r) a[r] = 0.f;
    const float* kp = Kt + (size_t)b * N_ * T_ + t0 + tl;
    for (int n = n0; n < n1; ++n) {
        float kv = kp[(size_t)n * T_];
#pragma unroll
        for (int r = 0; r < R_; ++r) {
            a[r] += kv * Ws[r * N_ + n];
            a[R_ + r] += kv * Ws[R_ * N_ + r * N_ + n];
        }
    }
#pragma unroll
    for (int r = 0; r < 2 * R_; ++r) part[g][tl][r] = a[r];
    __syncthreads();
    for (int o = threadIdx.x; o < 32 * 2 * R_; o += 256) {
        int tl2 = o / (2 * R_);
        int rr = o % (2 * R_);
        float s = 0.f;
#pragma unroll
        for (int gg = 0; gg < PG; ++gg) s += part[gg][tl2][rr];
        int t = t0 + tl2;
        if (rr < R_) KW1[((size_t)b * T_ + t) * R_ + rr] = s;
        else         QW2[((size_t)b * T_ + t) * R_ + rr - R_] = s;
    }
}

// ---------------------------------------------------------------------------
// Kernel 3: scores -> softmax -> Apk in MFMA A-operand fragment layout:
//   Apk[((b*18 + tt)*9 + st)*512 + (tl + 16*q)*8 + e] = A[b][t=tt*16+tl][s=st*32+q*8+e]
// ---------------------------------------------------------------------------
__global__ __launch_bounds__(64) void k_softmax(const float* __restrict__ KW1,
                                                const float* __restrict__ QW2,
                                                unsigned short* __restrict__ Apk) {
    __shared__ __align__(16) unsigned short sm[T_];
    int bt = blockIdx.x;
    int b = bt / T_;
    int t = bt % T_;
    int lane = threadIdx.x;
    float kw[R_];
#pragma unroll
    for (int r = 0; r < R_; ++r) kw[r] = KW1[bt * R_ + r];
    float sc[5];
    float mx = -1e30f;
#pragma unroll
    for (int j = 0; j < 5; ++j) {
        int s = lane + j * 64;
        float v = -1e30f;
        if (s < T_) {
            const float* q = QW2 + ((size_t)b * T_ + s) * R_;
            v = 0.f;
#pragma unroll
            for (int r = 0; r < R_; ++r) v += kw[r] * q[r];
        }
        sc[j] = v;
        mx = fmaxf(mx, v);
    }
#pragma unroll
    for (int off = 32; off > 0; off >>= 1) mx = fmaxf(mx, __shfl_xor(mx, off));
    float sum = 0.f;
#pragma unroll
    for (int j = 0; j < 5; ++j) {
        int s = lane + j * 64;
        float e = (s < T_) ? __expf(sc[j] - mx) : 0.f;
        sc[j] = e;
        sum += e;
    }
#pragma unroll
    for (int off = 32; off > 0; off >>= 1) sum += __shfl_xor(sum, off);
    float inv = 1.f / sum;
#pragma unroll
    for (int j = 0; j < 5; ++j) {
        int s = lane + j * 64;
        if (s < T_) sm[s] = f2bf(sc[j] * inv);
    }
    __syncthreads();
    if (lane < 36) {
        int st = lane >> 2, q = lane & 3;
        u32x4 v = *(const u32x4*)&sm[st * 32 + q * 8];
        int tt = t >> 4, tl = t & 15;
        size_t dst = ((((size_t)b * TT_ + tt) * ST_ + st) * 64 + tl + 16 * q) * 8;
        *(u32x4*)(Apk + dst) = v;
    }
}

// ---------------------------------------------------------------------------
// Kernel 4: out[b,m,t] = sum_s A[b,t,s]*X[b,m,s], mfma_f32_16x16x32_bf16,
// attention as A-operand. X panel staged to LDS once (NT reads). Flattened
// 27-step loop, rolling 4-deep A-fragment prefetch crossing chunk bounds.
// Coalesced f32x4 NT store epilogue.
// ---------------------------------------------------------------------------
template <int XBF>
__global__ __launch_bounds__(256, 4) void k_out(const float* __restrict__ xf,
                                                const unsigned short* __restrict__ xb,
                                                const unsigned short* __restrict__ Apk,
                                                float* __restrict__ out) {
    const int m0 = blockIdx.x * 64;
    const int b = blockIdx.y;

    __shared__ __align__(16) unsigned short Xs[64][296];  // 37,888 B

    const int tid = threadIdx.x;
    const int lane = tid & 63;
    const int wid = tid >> 6;
    const int wm = wid & 1;   // m half (32 rows)
    const int wt = wid >> 1;  // t half (48 of each 96-chunk)
    const int c = lane & 15;
    const int kq = lane >> 4;

    // ---- stage X panel (64 x 288) once; nontemporal reads ----
    {
        const size_t Xg = ((size_t)b * M_ + m0) * T_;
#pragma unroll
        for (int u = 0; u < 9; ++u) {
            int e = tid + u * 256;
            int row = e / 36;
            int ch = e % 36;
            if (XBF) {
                u32x4 v = __builtin_nontemporal_load((const u32x4*)(xb + Xg + (size_t)row * T_ + ch * 8));
                *(u32x4*)&Xs[row][ch * 8] = v;
            } else {
                f32x4 v0 = __builtin_nontemporal_load((const f32x4*)(xf + Xg + (size_t)row * T_ + ch * 8));
                f32x4 v1 = __builtin_nontemporal_load((const f32x4*)(xf + Xg + (size_t)row * T_ + ch * 8 + 4));
                *(u32x4*)&Xs[row][ch * 8] = pack8v(v0, v1);
            }
        }
    }
    __syncthreads();

    float* Ob = out + ((size_t)b * M_ + m0) * T_;
    const unsigned short* Abase =
        Apk + (((size_t)b * TT_ + wt * 3) * ST_) * 512 + (size_t)lane * 8;

    f32x4 acc[3][2];      // [t-frag][m-frag] for the CURRENT chunk
    bf16x8 abuf[4][3];    // rolling 4-deep prefetch

#pragma unroll
    for (int d = 0; d < 4; ++d)
#pragma unroll
        for (int j = 0; j < 3; ++j)
            abuf[d][j] = *(const bf16x8*)(Abase + ((size_t)(d / 9) * 6 + j) * (ST_ * 512) + (size_t)(d % 9) * 512);

#pragma unroll
    for (int it = 0; it < 27; ++it) {
        const int k = it % 9;
        const int chunk = it / 9;
        if (k == 0) {
#pragma unroll
            for (int j = 0; j < 3; ++j)
#pragma unroll
                for (int i = 0; i < 2; ++i) acc[j][i] = (f32x4){0.f, 0.f, 0.f, 0.f};
        }
        bf16x8 tmp[3];
        if (it + 4 < 27) {
            const int nit = it + 4;
#pragma unroll
            for (int j = 0; j < 3; ++j)
                tmp[j] = *(const bf16x8*)(Abase + ((size_t)(nit / 9) * 6 + j) * (ST_ * 512) + (size_t)(nit % 9) * 512);
        }
        bf16x8 x0 = *(const bf16x8*)&Xs[wm * 32 + c][k * 32 + kq * 8];
        bf16x8 x1 = *(const bf16x8*)&Xs[wm * 32 + 16 + c][k * 32 + kq * 8];
        __builtin_amdgcn_s_setprio(1);
        acc[0][0] = __builtin_amdgcn_mfma_f32_16x16x32_bf16(abuf[it % 4][0], x0, acc[0][0], 0, 0, 0);
        acc[0][1] = __builtin_amdgcn_mfma_f32_16x16x32_bf16(abuf[it % 4][0], x1, acc[0][1], 0, 0, 0);
        acc[1][0] = __builtin_amdgcn_mfma_f32_16x16x32_bf16(abuf[it % 4][1], x0, acc[1][0], 0, 0, 0);
        acc[1][1] = __builtin_amdgcn_mfma_f32_16x16x32_bf16(abuf[it % 4][1], x1, acc[1][1], 0, 0, 0);
        acc[2][0] = __builtin_amdgcn_mfma_f32_16x16x32_bf16(abuf[it % 4][2], x0, acc[2][0], 0, 0, 0);
        acc[2][1] = __builtin_amdgcn_mfma_f32_16x16x32_bf16(abuf[it % 4][2], x1, acc[2][1], 0, 0, 0);
        __builtin_amdgcn_s_setprio(0);
        if (it + 4 < 27) {
#pragma unroll
            for (int j = 0; j < 3; ++j) abuf[it % 4][j] = tmp[j];
        }
        if (k == 8) {
            const int tb = chunk * 96 + wt * 48;
#pragma unroll
            for (int j = 0; j < 3; ++j) {
                int t = tb + j * 16 + kq * 4;
#pragma unroll
                for (int i = 0; i < 2; ++i) {
                    int m = wm * 32 + i * 16 + c;
                    __builtin_nontemporal_store(acc[j][i], (f32x4*)&Ob[(size_t)m * T_ + t]);
                }
            }
        }
    }
}

// ---------------------------------------------------------------------------
extern "C" void kernel_launch(void* const* d_in, const int* in_sizes, int n_in,
                              void* d_out, int out_size, void* d_ws, size_t ws_size,
                              hipStream_t stream) {
    const float* x = (const float*)d_in[0];
    const float* W1 = (const float*)d_in[1];
    const float* W2 = (const float*)d_in[2];
    const float* alpha = (const float*)d_in[3];
    float* out = (float*)d_out;

    char* ws = (char*)d_ws;
    float* Kt = (float*)ws;                      ws += (size_t)B_ * N_ * T_ * 4;
    float* KW1 = (float*)ws;                     ws += (size_t)B_ * T_ * R_ * 4;
    float* QW2 = (float*)ws;                     ws += (size_t)B_ * T_ * R_ * 4;
    unsigned short* Apk = (unsigned short*)ws;   ws += (size_t)B_ * TT_ * ST_ * 512 * 2;
    unsigned short* xbf = (unsigned short*)ws;
    size_t need = (size_t)(ws - (char*)d_ws) + (size_t)B_ * C_ * N_ * T_ * 2;
    const bool use_bf = (ws_size >= need);

    {
        int total = B_ * N_ * (T_ / 4);
        int blks = (total + 255) / 256;
        if (use_bf)
            k_reduce<1><<<blks, 256, 0, stream>>>(x, alpha, Kt, xbf);
        else
            k_reduce<0><<<blks, 256, 0, stream>>>(x, alpha, Kt, xbf);
    }
    k_proj<<<B_ * (T_ / 32), 256, 0, stream>>>(Kt, W1, W2, KW1, QW2);
    k_softmax<<<B_ * T_, 64, 0, stream>>>(KW1, QW2, Apk);
    {
        dim3 grid(M_ / 64, B_);  // 307 x 16
        if (use_bf)
            k_out<1><<<grid, 256, 0, stream>>>(nullptr, xbf, Apk, out);
        else
            k_out<0><<<grid, 256, 0, stream>>>(x, nullptr, Apk, out);
    }
}

// Round 12
// 224.170 us; speedup vs baseline: 2.6733x; 1.0451x over previous
//
#include <hip/hip_runtime.h>

#define B_ 16
#define C_ 64
#define N_ 307
#define T_ 288
#define R_ 10
#define M_ (C_ * N_)   // 19648 = 307*64
#define TT_ (T_ / 16)  // 18 t-tiles
#define ST_ (T_ / 32)  // 9 k-tiles

typedef __attribute__((ext_vector_type(8))) short bf16x8;
typedef __attribute__((ext_vector_type(4))) float f32x4;
typedef __attribute__((ext_vector_type(4))) unsigned int u32x4;
typedef __attribute__((ext_vector_type(2))) unsigned int u32x2;

__device__ __forceinline__ unsigned short f2bf(float f) {
    unsigned int u = __float_as_uint(f);
    unsigned int r = (u + 0x7fffu + ((u >> 16) & 1u)) >> 16;  // RNE
    return (unsigned short)r;
}
__device__ __forceinline__ unsigned int pack2(float a, float b) {
    return (unsigned int)f2bf(a) | ((unsigned int)f2bf(b) << 16);
}
__device__ __forceinline__ u32x4 pack8v(f32x4 a, f32x4 b) {
    u32x4 w;
    w.x = pack2(a.x, a.y); w.y = pack2(a.z, a.w);
    w.z = pack2(b.x, b.y); w.w = pack2(b.z, b.w);
    return w;
}
// HW packed f32->bf16 (RNE), one VALU op for two elements
__device__ __forceinline__ unsigned int cvtpk2(float lo, float hi) {
    unsigned int r;
    asm("v_cvt_pk_bf16_f32 %0, %1, %2" : "=v"(r) : "v"(lo), "v"(hi));
    return r;
}

// ---------------------------------------------------------------------------
// Kernel 1: Kt[b,n,t] = sum_i alpha[i]*x[b,i,n,t] (coalesced writes), plus
// xbf = bf16(x) echo (stays L3-resident for k_out). x loads nontemporal.
// ---------------------------------------------------------------------------
template <int WRITE_BF>
__global__ __launch_bounds__(256) void k_reduce(const float* __restrict__ x,
                                                const float* __restrict__ alpha,
                                                float* __restrict__ Kt,
                                                unsigned short* __restrict__ xbf) {
    __shared__ float a_s[C_];
    if (threadIdx.x < C_) a_s[threadIdx.x] = alpha[threadIdx.x];
    __syncthreads();
    const int T4 = T_ / 4;  // 72
    int idx = blockIdx.x * blockDim.x + threadIdx.x;
    const int total = B_ * N_ * T4;
    if (idx >= total) return;
    int t4 = idx % T4;
    int n = (idx / T4) % N_;
    int b = idx / (N_ * T4);
    const size_t chs = (size_t)N_ * T_;
    size_t base = ((size_t)(b * C_) * N_ + n) * T_ + t4 * 4;
    f32x4 s = {0.f, 0.f, 0.f, 0.f};
#pragma unroll 8
    for (int i = 0; i < C_; ++i) {
        f32x4 v = __builtin_nontemporal_load((const f32x4*)(x + base + (size_t)i * chs));
        s += a_s[i] * v;
        if (WRITE_BF) {
            u32x2 w;
            w.x = cvtpk2(v.x, v.y);
            w.y = cvtpk2(v.z, v.w);
            *(u32x2*)(xbf + base + (size_t)i * chs) = w;
        }
    }
    *(f32x4*)(Kt + ((size_t)b * N_ + n) * T_ + t4 * 4) = s;
}

// ---------------------------------------------------------------------------
// Kernel 2: KW1[b,t,r], QW2[b,t,r] from Kt[b,n,t]. 144 blocks, 8-way n-split.
// ---------------------------------------------------------------------------
#define PG 8
__global__ __launch_bounds__(256) void k_proj(const float* __restrict__ Kt,
                                              const float* __restrict__ W1,
                                              const float* __restrict__ W2,
                                              float* __restrict__ KW1,
                                              float* __restrict__ QW2) {
    __shared__ float Ws[2 * R_ * N_];
    __shared__ float part[PG][32][2 * R_];
    for (int e = threadIdx.x; e < R_ * N_; e += 256) {
        Ws[e] = W1[e];
        Ws[R_ * N_ + e] = W2[e];
    }
    __syncthreads();
    int b = blockIdx.x / (T_ / 32);
    int tc = blockIdx.x % (T_ / 32);
    int t0 = tc * 32;
    int g = threadIdx.x >> 5;
    int tl = threadIdx.x & 31;
    int n0 = g * 38 + (g < 3 ? g : 3);
    int n1 = n0 + 38 + (g < 3 ? 1 : 0);
    float a[2 * R_];
#pragma unroll
    for (int r = 0; r < 2 * R_; ++r) a[r] = 0.f;
    const float* kp = Kt + (size_t)b * N_ * T_ + t0 + tl;
    for (int n = n0; n < n1; ++n) {
        float kv = kp[(size_t)n * T_];
#pragma unroll
        for (int r = 0; r < R_; ++r) {
            a[r] += kv * Ws[r * N_ + n];
            a[R_ + r] += kv * Ws[R_ * N_ + r * N_ + n];
        }
    }
#pragma unroll
    for (int r = 0; r < 2 * R_; ++r) part[g][tl][r] = a[r];
    __syncthreads();
    for (int o = threadIdx.x; o < 32 * 2 * R_; o += 256) {
        int tl2 = o / (2 * R_);
        int rr = o % (2 * R_);
        float s = 0.f;
#pragma unroll
        for (int gg = 0; gg < PG; ++gg) s += part[gg][tl2][rr];
        int t = t0 + tl2;
        if (rr < R_) KW1[((size_t)b * T_ + t) * R_ + rr] = s;
        else         QW2[((size_t)b * T_ + t) * R_ + rr - R_] = s;
    }
}

// ---------------------------------------------------------------------------
// Kernel 3: scores -> softmax -> Apk in MFMA A-operand fragment layout:
//   Apk[((b*18 + tt)*9 + st)*512 + (tl + 16*q)*8 + e] = A[b][t=tt*16+tl][s=st*32+q*8+e]
// ---------------------------------------------------------------------------
__global__ __launch_bounds__(64) void k_softmax(const float* __restrict__ KW1,
                                                const float* __restrict__ QW2,
                                                unsigned short* __restrict__ Apk) {
    __shared__ __align__(16) unsigned short sm[T_];
    int bt = blockIdx.x;
    int b = bt / T_;
    int t = bt % T_;
    int lane = threadIdx.x;
    float kw[R_];
#pragma unroll
    for (int r = 0; r < R_; ++r) kw[r] = KW1[bt * R_ + r];
    float sc[5];
    float mx = -1e30f;
#pragma unroll
    for (int j = 0; j < 5; ++j) {
        int s = lane + j * 64;
        float v = -1e30f;
        if (s < T_) {
            const float* q = QW2 + ((size_t)b * T_ + s) * R_;
            v = 0.f;
#pragma unroll
            for (int r = 0; r < R_; ++r) v += kw[r] * q[r];
        }
        sc[j] = v;
        mx = fmaxf(mx, v);
    }
#pragma unroll
    for (int off = 32; off > 0; off >>= 1) mx = fmaxf(mx, __shfl_xor(mx, off));
    float sum = 0.f;
#pragma unroll
    for (int j = 0; j < 5; ++j) {
        int s = lane + j * 64;
        float e = (s < T_) ? __expf(sc[j] - mx) : 0.f;
        sc[j] = e;
        sum += e;
    }
#pragma unroll
    for (int off = 32; off > 0; off >>= 1) sum += __shfl_xor(sum, off);
    float inv = 1.f / sum;
#pragma unroll
    for (int j = 0; j < 5; ++j) {
        int s = lane + j * 64;
        if (s < T_) sm[s] = f2bf(sc[j] * inv);
    }
    __syncthreads();
    if (lane < 36) {
        int st = lane >> 2, q = lane & 3;
        u32x4 v = *(const u32x4*)&sm[st * 32 + q * 8];
        int tt = t >> 4, tl = t & 15;
        size_t dst = ((((size_t)b * TT_ + tt) * ST_ + st) * 64 + tl + 16 * q) * 8;
        *(u32x4*)(Apk + dst) = v;
    }
}

// ---------------------------------------------------------------------------
// Kernel 4: out[b,m,t] = sum_s A[b,t,s]*X[b,m,s], mfma_f32_16x16x32_bf16.
// NEW geometry for occupancy: block = 32 m-rows x ALL 288 t, 384 threads =
// 6 waves, each wave owns 3 t-tiles x 2 m-frags for the whole 9-step K-loop
// (no chunk resets). LDS 19 KB -> ~5 blocks/CU (30 waves/CU vs 16 before):
// doubled TLP covers the A-fragment L2 latency that 4 waves/SIMD couldn't.
// A fragments: 1 coalesced dwordx4/lane, rolling 3-deep register prefetch.
// X staged once via NT loads; coalesced f32x4 NT store epilogue.
// ---------------------------------------------------------------------------
template <int XBF>
__global__ __launch_bounds__(384, 5) void k_out(const float* __restrict__ xf,
                                                const unsigned short* __restrict__ xb,
                                                const unsigned short* __restrict__ Apk,
                                                float* __restrict__ out) {
    const int m0 = blockIdx.x * 32;
    const int b = blockIdx.y;

    __shared__ __align__(16) unsigned short Xs[32][296];  // 18,944 B

    const int tid = threadIdx.x;
    const int lane = tid & 63;
    const int wid = tid >> 6;  // 0..5 -> t-tiles [wid*3, wid*3+3)
    const int c = lane & 15;
    const int kq = lane >> 4;

    // ---- stage X panel (32 x 288) once; 1152 16B units, 3 per thread ----
    {
        const size_t Xg = ((size_t)b * M_ + m0) * T_;
#pragma unroll
        for (int u = 0; u < 3; ++u) {
            int e = tid + u * 384;
            int row = e / 36;
            int ch = e % 36;
            if (XBF) {
                u32x4 v = __builtin_nontemporal_load((const u32x4*)(xb + Xg + (size_t)row * T_ + ch * 8));
                *(u32x4*)&Xs[row][ch * 8] = v;
            } else {
                f32x4 v0 = __builtin_nontemporal_load((const f32x4*)(xf + Xg + (size_t)row * T_ + ch * 8));
                f32x4 v1 = __builtin_nontemporal_load((const f32x4*)(xf + Xg + (size_t)row * T_ + ch * 8 + 4));
                *(u32x4*)&Xs[row][ch * 8] = pack8v(v0, v1);
            }
        }
    }
    __syncthreads();

    float* Ob = out + ((size_t)b * M_ + m0) * T_;
    const unsigned short* Abase =
        Apk + (((size_t)b * TT_ + wid * 3) * ST_) * 512 + (size_t)lane * 8;

    f32x4 acc[3][2];   // [t-frag][m-frag]
#pragma unroll
    for (int j = 0; j < 3; ++j)
#pragma unroll
        for (int i = 0; i < 2; ++i) acc[j][i] = (f32x4){0.f, 0.f, 0.f, 0.f};

    bf16x8 abuf[3][3];  // rolling 3-deep prefetch
#pragma unroll
    for (int d = 0; d < 3; ++d)
#pragma unroll
        for (int j = 0; j < 3; ++j)
            abuf[d][j] = *(const bf16x8*)(Abase + (size_t)j * (ST_ * 512) + (size_t)d * 512);

#pragma unroll
    for (int k = 0; k < 9; ++k) {
        bf16x8 tmp[3];
        if (k + 3 < 9) {
#pragma unroll
            for (int j = 0; j < 3; ++j)
                tmp[j] = *(const bf16x8*)(Abase + (size_t)j * (ST_ * 512) + (size_t)(k + 3) * 512);
        }
        bf16x8 x0 = *(const bf16x8*)&Xs[c][k * 32 + kq * 8];
        bf16x8 x1 = *(const bf16x8*)&Xs[16 + c][k * 32 + kq * 8];
        __builtin_amdgcn_s_setprio(1);
        acc[0][0] = __builtin_amdgcn_mfma_f32_16x16x32_bf16(abuf[k % 3][0], x0, acc[0][0], 0, 0, 0);
        acc[0][1] = __builtin_amdgcn_mfma_f32_16x16x32_bf16(abuf[k % 3][0], x1, acc[0][1], 0, 0, 0);
        acc[1][0] = __builtin_amdgcn_mfma_f32_16x16x32_bf16(abuf[k % 3][1], x0, acc[1][0], 0, 0, 0);
        acc[1][1] = __builtin_amdgcn_mfma_f32_16x16x32_bf16(abuf[k % 3][1], x1, acc[1][1], 0, 0, 0);
        acc[2][0] = __builtin_amdgcn_mfma_f32_16x16x32_bf16(abuf[k % 3][2], x0, acc[2][0], 0, 0, 0);
        acc[2][1] = __builtin_amdgcn_mfma_f32_16x16x32_bf16(abuf[k % 3][2], x1, acc[2][1], 0, 0, 0);
        __builtin_amdgcn_s_setprio(0);
        if (k + 3 < 9) {
#pragma unroll
            for (int j = 0; j < 3; ++j) abuf[k % 3][j] = tmp[j];
        }
    }

#pragma unroll
    for (int j = 0; j < 3; ++j) {
        int t = wid * 48 + j * 16 + kq * 4;
#pragma unroll
        for (int i = 0; i < 2; ++i) {
            int m = i * 16 + c;
            __builtin_nontemporal_store(acc[j][i], (f32x4*)&Ob[(size_t)m * T_ + t]);
        }
    }
}

// ---------------------------------------------------------------------------
extern "C" void kernel_launch(void* const* d_in, const int* in_sizes, int n_in,
                              void* d_out, int out_size, void* d_ws, size_t ws_size,
                              hipStream_t stream) {
    const float* x = (const float*)d_in[0];
    const float* W1 = (const float*)d_in[1];
    const float* W2 = (const float*)d_in[2];
    const float* alpha = (const float*)d_in[3];
    float* out = (float*)d_out;

    char* ws = (char*)d_ws;
    float* Kt = (float*)ws;                      ws += (size_t)B_ * N_ * T_ * 4;
    float* KW1 = (float*)ws;                     ws += (size_t)B_ * T_ * R_ * 4;
    float* QW2 = (float*)ws;                     ws += (size_t)B_ * T_ * R_ * 4;
    unsigned short* Apk = (unsigned short*)ws;   ws += (size_t)B_ * TT_ * ST_ * 512 * 2;
    unsigned short* xbf = (unsigned short*)ws;
    size_t need = (size_t)(ws - (char*)d_ws) + (size_t)B_ * C_ * N_ * T_ * 2;
    const bool use_bf = (ws_size >= need);

    {
        int total = B_ * N_ * (T_ / 4);
        int blks = (total + 255) / 256;
        if (use_bf)
            k_reduce<1><<<blks, 256, 0, stream>>>(x, alpha, Kt, xbf);
        else
            k_reduce<0><<<blks, 256, 0, stream>>>(x, alpha, Kt, xbf);
    }
    k_proj<<<B_ * (T_ / 32), 256, 0, stream>>>(Kt, W1, W2, KW1, QW2);
    k_softmax<<<B_ * T_, 64, 0, stream>>>(KW1, QW2, Apk);
    {
        dim3 grid(M_ / 32, B_);  // 614 x 16
        if (use_bf)
            k_out<1><<<grid, 384, 0, stream>>>(nullptr, xbf, Apk, out);
        else
            k_out<0><<<grid, 384, 0, stream>>>(x, nullptr, Apk, out);
    }
}

// Round 13
// 222.969 us; speedup vs baseline: 2.6877x; 1.0054x over previous
//
#include <hip/hip_runtime.h>

#define B_ 16
#define C_ 64
#define N_ 307
#define T_ 288
#define R_ 10
#define M_ (C_ * N_)   // 19648 = 307*64
#define TT_ (T_ / 16)  // 18 t-tiles
#define ST_ (T_ / 32)  // 9 k-tiles

typedef __attribute__((ext_vector_type(8))) short bf16x8;
typedef __attribute__((ext_vector_type(4))) float f32x4;
typedef __attribute__((ext_vector_type(4))) unsigned int u32x4;
typedef __attribute__((ext_vector_type(2))) unsigned int u32x2;

__device__ __forceinline__ unsigned short f2bf(float f) {
    unsigned int u = __float_as_uint(f);
    unsigned int r = (u + 0x7fffu + ((u >> 16) & 1u)) >> 16;  // RNE
    return (unsigned short)r;
}
__device__ __forceinline__ unsigned int pack2(float a, float b) {
    return (unsigned int)f2bf(a) | ((unsigned int)f2bf(b) << 16);
}
__device__ __forceinline__ u32x4 pack8v(f32x4 a, f32x4 b) {
    u32x4 w;
    w.x = pack2(a.x, a.y); w.y = pack2(a.z, a.w);
    w.z = pack2(b.x, b.y); w.w = pack2(b.z, b.w);
    return w;
}
// HW packed f32->bf16 (RNE), one VALU op for two elements
__device__ __forceinline__ unsigned int cvtpk2(float lo, float hi) {
    unsigned int r;
    asm("v_cvt_pk_bf16_f32 %0, %1, %2" : "=v"(r) : "v"(lo), "v"(hi));
    return r;
}

// ---------------------------------------------------------------------------
// Kernel 1: Kt[b,n,t] = sum_i alpha[i]*x[b,i,n,t] (coalesced writes), plus
// xbf = bf16(x) echo (stays L3-resident for k_out). x loads nontemporal.
// alpha read DIRECTLY (wave-uniform -> scalar s_load into SGPRs, hoisted by
// the unroller) instead of per-iter LDS reads: removes 64 ds_read_b32 +
// lgkmcnt waits per thread from the load/store stream.
// ---------------------------------------------------------------------------
template <int WRITE_BF>
__global__ __launch_bounds__(256) void k_reduce(const float* __restrict__ x,
                                                const float* __restrict__ alpha,
                                                float* __restrict__ Kt,
                                                unsigned short* __restrict__ xbf) {
    const int T4 = T_ / 4;  // 72
    int idx = blockIdx.x * blockDim.x + threadIdx.x;
    const int total = B_ * N_ * T4;
    if (idx >= total) return;
    int t4 = idx % T4;
    int n = (idx / T4) % N_;
    int b = idx / (N_ * T4);
    const size_t chs = (size_t)N_ * T_;
    size_t base = ((size_t)(b * C_) * N_ + n) * T_ + t4 * 4;
    f32x4 s = {0.f, 0.f, 0.f, 0.f};
#pragma unroll 8
    for (int i = 0; i < C_; ++i) {
        f32x4 v = __builtin_nontemporal_load((const f32x4*)(x + base + (size_t)i * chs));
        s += alpha[i] * v;
        if (WRITE_BF) {
            u32x2 w;
            w.x = cvtpk2(v.x, v.y);
            w.y = cvtpk2(v.z, v.w);
            *(u32x2*)(xbf + base + (size_t)i * chs) = w;
        }
    }
    *(f32x4*)(Kt + ((size_t)b * N_ + n) * T_ + t4 * 4) = s;
}

// ---------------------------------------------------------------------------
// Kernel 2: KW1[b,t,r], QW2[b,t,r] from Kt[b,n,t]. 144 blocks, 8-way n-split.
// ---------------------------------------------------------------------------
#define PG 8
__global__ __launch_bounds__(256) void k_proj(const float* __restrict__ Kt,
                                              const float* __restrict__ W1,
                                              const float* __restrict__ W2,
                                              float* __restrict__ KW1,
                                              float* __restrict__ QW2) {
    __shared__ float Ws[2 * R_ * N_];
    __shared__ float part[PG][32][2 * R_];
    for (int e = threadIdx.x; e < R_ * N_; e += 256) {
        Ws[e] = W1[e];
        Ws[R_ * N_ + e] = W2[e];
    }
    __syncthreads();
    int b = blockIdx.x / (T_ / 32);
    int tc = blockIdx.x % (T_ / 32);
    int t0 = tc * 32;
    int g = threadIdx.x >> 5;
    int tl = threadIdx.x & 31;
    int n0 = g * 38 + (g < 3 ? g : 3);
    int n1 = n0 + 38 + (g < 3 ? 1 : 0);
    float a[2 * R_];
#pragma unroll
    for (int r = 0; r < 2 * R_; ++r) a[r] = 0.f;
    const float* kp = Kt + (size_t)b * N_ * T_ + t0 + tl;
    for (int n = n0; n < n1; ++n) {
        float kv = kp[(size_t)n * T_];
#pragma unroll
        for (int r = 0; r < R_; ++r) {
            a[r] += kv * Ws[r * N_ + n];
            a[R_ + r] += kv * Ws[R_ * N_ + r * N_ + n];
        }
    }
#pragma unroll
    for (int r = 0; r < 2 * R_; ++r) part[g][tl][r] = a[r];
    __syncthreads();
    for (int o = threadIdx.x; o < 32 * 2 * R_; o += 256) {
        int tl2 = o / (2 * R_);
        int rr = o % (2 * R_);
        float s = 0.f;
#pragma unroll
        for (int gg = 0; gg < PG; ++gg) s += part[gg][tl2][rr];
        int t = t0 + tl2;
        if (rr < R_) KW1[((size_t)b * T_ + t) * R_ + rr] = s;
        else         QW2[((size_t)b * T_ + t) * R_ + rr - R_] = s;
    }
}

// ---------------------------------------------------------------------------
// Kernel 3: scores -> softmax -> Apk in MFMA A-operand fragment layout:
//   Apk[((b*18 + tt)*9 + st)*512 + (tl + 16*q)*8 + e] = A[b][t=tt*16+tl][s=st*32+q*8+e]
// ---------------------------------------------------------------------------
__global__ __launch_bounds__(64) void k_softmax(const float* __restrict__ KW1,
                                                const float* __restrict__ QW2,
                                                unsigned short* __restrict__ Apk) {
    __shared__ __align__(16) unsigned short sm[T_];
    int bt = blockIdx.x;
    int b = bt / T_;
    int t = bt % T_;
    int lane = threadIdx.x;
    float kw[R_];
#pragma unroll
    for (int r = 0; r < R_; ++r) kw[r] = KW1[bt * R_ + r];
    float sc[5];
    float mx = -1e30f;
#pragma unroll
    for (int j = 0; j < 5; ++j) {
        int s = lane + j * 64;
        float v = -1e30f;
        if (s < T_) {
            const float* q = QW2 + ((size_t)b * T_ + s) * R_;
            v = 0.f;
#pragma unroll
            for (int r = 0; r < R_; ++r) v += kw[r] * q[r];
        }
        sc[j] = v;
        mx = fmaxf(mx, v);
    }
#pragma unroll
    for (int off = 32; off > 0; off >>= 1) mx = fmaxf(mx, __shfl_xor(mx, off));
    float sum = 0.f;
#pragma unroll
    for (int j = 0; j < 5; ++j) {
        int s = lane + j * 64;
        float e = (s < T_) ? __expf(sc[j] - mx) : 0.f;
        sc[j] = e;
        sum += e;
    }
#pragma unroll
    for (int off = 32; off > 0; off >>= 1) sum += __shfl_xor(sum, off);
    float inv = 1.f / sum;
#pragma unroll
    for (int j = 0; j < 5; ++j) {
        int s = lane + j * 64;
        if (s < T_) sm[s] = f2bf(sc[j] * inv);
    }
    __syncthreads();
    if (lane < 36) {
        int st = lane >> 2, q = lane & 3;
        u32x4 v = *(const u32x4*)&sm[st * 32 + q * 8];
        int tt = t >> 4, tl = t & 15;
        size_t dst = ((((size_t)b * TT_ + tt) * ST_ + st) * 64 + tl + 16 * q) * 8;
        *(u32x4*)(Apk + dst) = v;
    }
}

// ---------------------------------------------------------------------------
// Kernel 4: out[b,m,t] = sum_s A[b,t,s]*X[b,m,s], mfma_f32_16x16x32_bf16.
// Block = 32 m-rows x ALL 288 t, 384 threads = 6 waves; each wave owns
// 3 t-tiles x 2 m-frags for the whole 9-step K-loop. LDS 19 KB -> 5 blocks/CU
// (30 waves/CU). A fragments: 1 coalesced dwordx4/lane, rolling 3-deep
// register prefetch. X staged once (NT loads); coalesced f32x4 NT stores.
// ---------------------------------------------------------------------------
template <int XBF>
__global__ __launch_bounds__(384, 5) void k_out(const float* __restrict__ xf,
                                                const unsigned short* __restrict__ xb,
                                                const unsigned short* __restrict__ Apk,
                                                float* __restrict__ out) {
    const int m0 = blockIdx.x * 32;
    const int b = blockIdx.y;

    __shared__ __align__(16) unsigned short Xs[32][296];  // 18,944 B

    const int tid = threadIdx.x;
    const int lane = tid & 63;
    const int wid = tid >> 6;  // 0..5 -> t-tiles [wid*3, wid*3+3)
    const int c = lane & 15;
    const int kq = lane >> 4;

    // ---- stage X panel (32 x 288) once; 1152 16B units, 3 per thread ----
    {
        const size_t Xg = ((size_t)b * M_ + m0) * T_;
#pragma unroll
        for (int u = 0; u < 3; ++u) {
            int e = tid + u * 384;
            int row = e / 36;
            int ch = e % 36;
            if (XBF) {
                u32x4 v = __builtin_nontemporal_load((const u32x4*)(xb + Xg + (size_t)row * T_ + ch * 8));
                *(u32x4*)&Xs[row][ch * 8] = v;
            } else {
                f32x4 v0 = __builtin_nontemporal_load((const f32x4*)(xf + Xg + (size_t)row * T_ + ch * 8));
                f32x4 v1 = __builtin_nontemporal_load((const f32x4*)(xf + Xg + (size_t)row * T_ + ch * 8 + 4));
                *(u32x4*)&Xs[row][ch * 8] = pack8v(v0, v1);
            }
        }
    }
    __syncthreads();

    float* Ob = out + ((size_t)b * M_ + m0) * T_;
    const unsigned short* Abase =
        Apk + (((size_t)b * TT_ + wid * 3) * ST_) * 512 + (size_t)lane * 8;

    f32x4 acc[3][2];   // [t-frag][m-frag]
#pragma unroll
    for (int j = 0; j < 3; ++j)
#pragma unroll
        for (int i = 0; i < 2; ++i) acc[j][i] = (f32x4){0.f, 0.f, 0.f, 0.f};

    bf16x8 abuf[3][3];  // rolling 3-deep prefetch
#pragma unroll
    for (int d = 0; d < 3; ++d)
#pragma unroll
        for (int j = 0; j < 3; ++j)
            abuf[d][j] = *(const bf16x8*)(Abase + (size_t)j * (ST_ * 512) + (size_t)d * 512);

#pragma unroll
    for (int k = 0; k < 9; ++k) {
        bf16x8 tmp[3];
        if (k + 3 < 9) {
#pragma unroll
            for (int j = 0; j < 3; ++j)
                tmp[j] = *(const bf16x8*)(Abase + (size_t)j * (ST_ * 512) + (size_t)(k + 3) * 512);
        }
        bf16x8 x0 = *(const bf16x8*)&Xs[c][k * 32 + kq * 8];
        bf16x8 x1 = *(const bf16x8*)&Xs[16 + c][k * 32 + kq * 8];
        __builtin_amdgcn_s_setprio(1);
        acc[0][0] = __builtin_amdgcn_mfma_f32_16x16x32_bf16(abuf[k % 3][0], x0, acc[0][0], 0, 0, 0);
        acc[0][1] = __builtin_amdgcn_mfma_f32_16x16x32_bf16(abuf[k % 3][0], x1, acc[0][1], 0, 0, 0);
        acc[1][0] = __builtin_amdgcn_mfma_f32_16x16x32_bf16(abuf[k % 3][1], x0, acc[1][0], 0, 0, 0);
        acc[1][1] = __builtin_amdgcn_mfma_f32_16x16x32_bf16(abuf[k % 3][1], x1, acc[1][1], 0, 0, 0);
        acc[2][0] = __builtin_amdgcn_mfma_f32_16x16x32_bf16(abuf[k % 3][2], x0, acc[2][0], 0, 0, 0);
        acc[2][1] = __builtin_amdgcn_mfma_f32_16x16x32_bf16(abuf[k % 3][2], x1, acc[2][1], 0, 0, 0);
        __builtin_amdgcn_s_setprio(0);
        if (k + 3 < 9) {
#pragma unroll
            for (int j = 0; j < 3; ++j) abuf[k % 3][j] = tmp[j];
        }
    }

#pragma unroll
    for (int j = 0; j < 3; ++j) {
        int t = wid * 48 + j * 16 + kq * 4;
#pragma unroll
        for (int i = 0; i < 2; ++i) {
            int m = i * 16 + c;
            __builtin_nontemporal_store(acc[j][i], (f32x4*)&Ob[(size_t)m * T_ + t]);
        }
    }
}

// ---------------------------------------------------------------------------
extern "C" void kernel_launch(void* const* d_in, const int* in_sizes, int n_in,
                              void* d_out, int out_size, void* d_ws, size_t ws_size,
                              hipStream_t stream) {
    const float* x = (const float*)d_in[0];
    const float* W1 = (const float*)d_in[1];
    const float* W2 = (const float*)d_in[2];
    const float* alpha = (const float*)d_in[3];
    float* out = (float*)d_out;

    char* ws = (char*)d_ws;
    float* Kt = (float*)ws;                      ws += (size_t)B_ * N_ * T_ * 4;
    float* KW1 = (float*)ws;                     ws += (size_t)B_ * T_ * R_ * 4;
    float* QW2 = (float*)ws;                     ws += (size_t)B_ * T_ * R_ * 4;
    unsigned short* Apk = (unsigned short*)ws;   ws += (size_t)B_ * TT_ * ST_ * 512 * 2;
    unsigned short* xbf = (unsigned short*)ws;
    size_t need = (size_t)(ws - (char*)d_ws) + (size_t)B_ * C_ * N_ * T_ * 2;
    const bool use_bf = (ws_size >= need);

    {
        int total = B_ * N_ * (T_ / 4);
        int blks = (total + 255) / 256;
        if (use_bf)
            k_reduce<1><<<blks, 256, 0, stream>>>(x, alpha, Kt, xbf);
        else
            k_reduce<0><<<blks, 256, 0, stream>>>(x, alpha, Kt, xbf);
    }
    k_proj<<<B_ * (T_ / 32), 256, 0, stream>>>(Kt, W1, W2, KW1, QW2);
    k_softmax<<<B_ * T_, 64, 0, stream>>>(KW1, QW2, Apk);
    {
        dim3 grid(M_ / 32, B_);  // 614 x 16
        if (use_bf)
            k_out<1><<<grid, 384, 0, stream>>>(nullptr, xbf, Apk, out);
        else
            k_out<0><<<grid, 384, 0, stream>>>(x, nullptr, Apk, out);
    }
}

// Round 14
// 221.882 us; speedup vs baseline: 2.7009x; 1.0049x over previous
//
#include <hip/hip_runtime.h>

#define B_ 16
#define C_ 64
#define N_ 307
#define T_ 288
#define R_ 10
#define M_ (C_ * N_)   // 19648 = 307*64
#define TT_ (T_ / 16)  // 18 t-tiles
#define ST_ (T_ / 32)  // 9 k-tiles

typedef __attribute__((ext_vector_type(8))) short bf16x8;
typedef __attribute__((ext_vector_type(4))) float f32x4;
typedef __attribute__((ext_vector_type(4))) unsigned int u32x4;
typedef __attribute__((ext_vector_type(2))) unsigned int u32x2;

__device__ __forceinline__ unsigned short f2bf(float f) {
    unsigned int u = __float_as_uint(f);
    unsigned int r = (u + 0x7fffu + ((u >> 16) & 1u)) >> 16;  // RNE
    return (unsigned short)r;
}
__device__ __forceinline__ unsigned int pack2(float a, float b) {
    return (unsigned int)f2bf(a) | ((unsigned int)f2bf(b) << 16);
}
__device__ __forceinline__ u32x4 pack8v(f32x4 a, f32x4 b) {
    u32x4 w;
    w.x = pack2(a.x, a.y); w.y = pack2(a.z, a.w);
    w.z = pack2(b.x, b.y); w.w = pack2(b.z, b.w);
    return w;
}
// HW packed f32->bf16 (RNE), one VALU op for two elements
__device__ __forceinline__ unsigned int cvtpk2(float lo, float hi) {
    unsigned int r;
    asm("v_cvt_pk_bf16_f32 %0, %1, %2" : "=v"(r) : "v"(lo), "v"(hi));
    return r;
}

// ---------------------------------------------------------------------------
// Kernel 1: Kt[b,n,t] = sum_i alpha[i]*x[b,i,n,t] + xbf = bf16(x) echo.
// CHANNEL-SPLIT for TLP: each (b,n,t4) handled by TWO threads (32 channels
// each) -> 708k threads (wave cap saturated), serial load chain halved.
// tid<128 = c-half 0 of 128 (n,t4) pairs; tid>=128 = c-half 1 of the same
// pairs (lanes stay consecutive-t4 -> xbf writes fully coalesced).
// Partner partials combined through LDS; low half stores Kt.
// ---------------------------------------------------------------------------
template <int WRITE_BF>
__global__ __launch_bounds__(256) void k_reduce(const float* __restrict__ x,
                                                const float* __restrict__ alpha,
                                                float* __restrict__ Kt,
                                                unsigned short* __restrict__ xbf) {
    __shared__ __align__(16) float part[256][4];
    const int T4 = T_ / 4;  // 72
    const int tid = threadIdx.x;
    const int half = tid >> 7;       // 0 or 1 (channel half)
    const int sub = tid & 127;       // which (n,t4) pair in this block
    int pair = blockIdx.x * 128 + sub;  // 0 .. B*N*T4-1 (2764 blocks exact)
    int t4 = pair % T4;
    int n = (pair / T4) % N_;
    int b = pair / (N_ * T4);
    const size_t chs = (size_t)N_ * T_;
    size_t base = ((size_t)(b * C_) * N_ + n) * T_ + t4 * 4 + (size_t)(half * 32) * chs;
    f32x4 s = {0.f, 0.f, 0.f, 0.f};
#pragma unroll 8
    for (int i = 0; i < 32; ++i) {
        f32x4 v = __builtin_nontemporal_load((const f32x4*)(x + base + (size_t)i * chs));
        s += alpha[half * 32 + i] * v;
        if (WRITE_BF) {
            u32x2 w;
            w.x = cvtpk2(v.x, v.y);
            w.y = cvtpk2(v.z, v.w);
            *(u32x2*)(xbf + base + (size_t)i * chs) = w;
        }
    }
    *(f32x4*)part[tid] = s;
    __syncthreads();
    if (half == 0) {
        f32x4 o = *(const f32x4*)part[tid + 128];
        s += o;
        *(f32x4*)(Kt + ((size_t)b * N_ + n) * T_ + t4 * 4) = s;
    }
}

// ---------------------------------------------------------------------------
// Kernel 2: KW1[b,t,r], QW2[b,t,r] from Kt[b,n,t]. 144 blocks, 8-way n-split.
// ---------------------------------------------------------------------------
#define PG 8
__global__ __launch_bounds__(256) void k_proj(const float* __restrict__ Kt,
                                              const float* __restrict__ W1,
                                              const float* __restrict__ W2,
                                              float* __restrict__ KW1,
                                              float* __restrict__ QW2) {
    __shared__ float Ws[2 * R_ * N_];
    __shared__ float part[PG][32][2 * R_];
    for (int e = threadIdx.x; e < R_ * N_; e += 256) {
        Ws[e] = W1[e];
        Ws[R_ * N_ + e] = W2[e];
    }
    __syncthreads();
    int b = blockIdx.x / (T_ / 32);
    int tc = blockIdx.x % (T_ / 32);
    int t0 = tc * 32;
    int g = threadIdx.x >> 5;
    int tl = threadIdx.x & 31;
    int n0 = g * 38 + (g < 3 ? g : 3);
    int n1 = n0 + 38 + (g < 3 ? 1 : 0);
    float a[2 * R_];
#pragma unroll
    for (int r = 0; r < 2 * R_; ++r) a[r] = 0.f;
    const float* kp = Kt + (size_t)b * N_ * T_ + t0 + tl;
    for (int n = n0; n < n1; ++n) {
        float kv = kp[(size_t)n * T_];
#pragma unroll
        for (int r = 0; r < R_; ++r) {
            a[r] += kv * Ws[r * N_ + n];
            a[R_ + r] += kv * Ws[R_ * N_ + r * N_ + n];
        }
    }
#pragma unroll
    for (int r = 0; r < 2 * R_; ++r) part[g][tl][r] = a[r];
    __syncthreads();
    for (int o = threadIdx.x; o < 32 * 2 * R_; o += 256) {
        int tl2 = o / (2 * R_);
        int rr = o % (2 * R_);
        float s = 0.f;
#pragma unroll
        for (int gg = 0; gg < PG; ++gg) s += part[gg][tl2][rr];
        int t = t0 + tl2;
        if (rr < R_) KW1[((size_t)b * T_ + t) * R_ + rr] = s;
        else         QW2[((size_t)b * T_ + t) * R_ + rr - R_] = s;
    }
}

// ---------------------------------------------------------------------------
// Kernel 3: scores -> softmax -> Apk in MFMA A-operand fragment layout:
//   Apk[((b*18 + tt)*9 + st)*512 + (tl + 16*q)*8 + e] = A[b][t=tt*16+tl][s=st*32+q*8+e]
// ---------------------------------------------------------------------------
__global__ __launch_bounds__(64) void k_softmax(const float* __restrict__ KW1,
                                                const float* __restrict__ QW2,
                                                unsigned short* __restrict__ Apk) {
    __shared__ __align__(16) unsigned short sm[T_];
    int bt = blockIdx.x;
    int b = bt / T_;
    int t = bt % T_;
    int lane = threadIdx.x;
    float kw[R_];
#pragma unroll
    for (int r = 0; r < R_; ++r) kw[r] = KW1[bt * R_ + r];
    float sc[5];
    float mx = -1e30f;
#pragma unroll
    for (int j = 0; j < 5; ++j) {
        int s = lane + j * 64;
        float v = -1e30f;
        if (s < T_) {
            const float* q = QW2 + ((size_t)b * T_ + s) * R_;
            v = 0.f;
#pragma unroll
            for (int r = 0; r < R_; ++r) v += kw[r] * q[r];
        }
        sc[j] = v;
        mx = fmaxf(mx, v);
    }
#pragma unroll
    for (int off = 32; off > 0; off >>= 1) mx = fmaxf(mx, __shfl_xor(mx, off));
    float sum = 0.f;
#pragma unroll
    for (int j = 0; j < 5; ++j) {
        int s = lane + j * 64;
        float e = (s < T_) ? __expf(sc[j] - mx) : 0.f;
        sc[j] = e;
        sum += e;
    }
#pragma unroll
    for (int off = 32; off > 0; off >>= 1) sum += __shfl_xor(sum, off);
    float inv = 1.f / sum;
#pragma unroll
    for (int j = 0; j < 5; ++j) {
        int s = lane + j * 64;
        if (s < T_) sm[s] = f2bf(sc[j] * inv);
    }
    __syncthreads();
    if (lane < 36) {
        int st = lane >> 2, q = lane & 3;
        u32x4 v = *(const u32x4*)&sm[st * 32 + q * 8];
        int tt = t >> 4, tl = t & 15;
        size_t dst = ((((size_t)b * TT_ + tt) * ST_ + st) * 64 + tl + 16 * q) * 8;
        *(u32x4*)(Apk + dst) = v;
    }
}

// ---------------------------------------------------------------------------
// Kernel 4: out[b,m,t] = sum_s A[b,t,s]*X[b,m,s], mfma_f32_16x16x32_bf16.
// Block = 32 m-rows x ALL 288 t, 384 threads = 6 waves; each wave owns
// 3 t-tiles x 2 m-frags for the whole 9-step K-loop. LDS 19 KB -> 5 blocks/CU
// (30 waves/CU). A fragments: 1 coalesced dwordx4/lane, rolling 3-deep
// register prefetch. X staged once (NT loads); coalesced f32x4 NT stores.
// ---------------------------------------------------------------------------
template <int XBF>
__global__ __launch_bounds__(384, 5) void k_out(const float* __restrict__ xf,
                                                const unsigned short* __restrict__ xb,
                                                const unsigned short* __restrict__ Apk,
                                                float* __restrict__ out) {
    const int m0 = blockIdx.x * 32;
    const int b = blockIdx.y;

    __shared__ __align__(16) unsigned short Xs[32][296];  // 18,944 B

    const int tid = threadIdx.x;
    const int lane = tid & 63;
    const int wid = tid >> 6;  // 0..5 -> t-tiles [wid*3, wid*3+3)
    const int c = lane & 15;
    const int kq = lane >> 4;

    // ---- stage X panel (32 x 288) once; 1152 16B units, 3 per thread ----
    {
        const size_t Xg = ((size_t)b * M_ + m0) * T_;
#pragma unroll
        for (int u = 0; u < 3; ++u) {
            int e = tid + u * 384;
            int row = e / 36;
            int ch = e % 36;
            if (XBF) {
                u32x4 v = __builtin_nontemporal_load((const u32x4*)(xb + Xg + (size_t)row * T_ + ch * 8));
                *(u32x4*)&Xs[row][ch * 8] = v;
            } else {
                f32x4 v0 = __builtin_nontemporal_load((const f32x4*)(xf + Xg + (size_t)row * T_ + ch * 8));
                f32x4 v1 = __builtin_nontemporal_load((const f32x4*)(xf + Xg + (size_t)row * T_ + ch * 8 + 4));
                *(u32x4*)&Xs[row][ch * 8] = pack8v(v0, v1);
            }
        }
    }
    __syncthreads();

    float* Ob = out + ((size_t)b * M_ + m0) * T_;
    const unsigned short* Abase =
        Apk + (((size_t)b * TT_ + wid * 3) * ST_) * 512 + (size_t)lane * 8;

    f32x4 acc[3][2];   // [t-frag][m-frag]
#pragma unroll
    for (int j = 0; j < 3; ++j)
#pragma unroll
        for (int i = 0; i < 2; ++i) acc[j][i] = (f32x4){0.f, 0.f, 0.f, 0.f};

    bf16x8 abuf[3][3];  // rolling 3-deep prefetch
#pragma unroll
    for (int d = 0; d < 3; ++d)
#pragma unroll
        for (int j = 0; j < 3; ++j)
            abuf[d][j] = *(const bf16x8*)(Abase + (size_t)j * (ST_ * 512) + (size_t)d * 512);

#pragma unroll
    for (int k = 0; k < 9; ++k) {
        bf16x8 tmp[3];
        if (k + 3 < 9) {
#pragma unroll
            for (int j = 0; j < 3; ++j)
                tmp[j] = *(const bf16x8*)(Abase + (size_t)j * (ST_ * 512) + (size_t)(k + 3) * 512);
        }
        bf16x8 x0 = *(const bf16x8*)&Xs[c][k * 32 + kq * 8];
        bf16x8 x1 = *(const bf16x8*)&Xs[16 + c][k * 32 + kq * 8];
        __builtin_amdgcn_s_setprio(1);
        acc[0][0] = __builtin_amdgcn_mfma_f32_16x16x32_bf16(abuf[k % 3][0], x0, acc[0][0], 0, 0, 0);
        acc[0][1] = __builtin_amdgcn_mfma_f32_16x16x32_bf16(abuf[k % 3][0], x1, acc[0][1], 0, 0, 0);
        acc[1][0] = __builtin_amdgcn_mfma_f32_16x16x32_bf16(abuf[k % 3][1], x0, acc[1][0], 0, 0, 0);
        acc[1][1] = __builtin_amdgcn_mfma_f32_16x16x32_bf16(abuf[k % 3][1], x1, acc[1][1], 0, 0, 0);
        acc[2][0] = __builtin_amdgcn_mfma_f32_16x16x32_bf16(abuf[k % 3][2], x0, acc[2][0], 0, 0, 0);
        acc[2][1] = __builtin_amdgcn_mfma_f32_16x16x32_bf16(abuf[k % 3][2], x1, acc[2][1], 0, 0, 0);
        __builtin_amdgcn_s_setprio(0);
        if (k + 3 < 9) {
#pragma unroll
            for (int j = 0; j < 3; ++j) abuf[k % 3][j] = tmp[j];
        }
    }

#pragma unroll
    for (int j = 0; j < 3; ++j) {
        int t = wid * 48 + j * 16 + kq * 4;
#pragma unroll
        for (int i = 0; i < 2; ++i) {
            int m = i * 16 + c;
            __builtin_nontemporal_store(acc[j][i], (f32x4*)&Ob[(size_t)m * T_ + t]);
        }
    }
}

// ---------------------------------------------------------------------------
extern "C" void kernel_launch(void* const* d_in, const int* in_sizes, int n_in,
                              void* d_out, int out_size, void* d_ws, size_t ws_size,
                              hipStream_t stream) {
    const float* x = (const float*)d_in[0];
    const float* W1 = (const float*)d_in[1];
    const float* W2 = (const float*)d_in[2];
    const float* alpha = (const float*)d_in[3];
    float* out = (float*)d_out;

    char* ws = (char*)d_ws;
    float* Kt = (float*)ws;                      ws += (size_t)B_ * N_ * T_ * 4;
    float* KW1 = (float*)ws;                     ws += (size_t)B_ * T_ * R_ * 4;
    float* QW2 = (float*)ws;                     ws += (size_t)B_ * T_ * R_ * 4;
    unsigned short* Apk = (unsigned short*)ws;   ws += (size_t)B_ * TT_ * ST_ * 512 * 2;
    unsigned short* xbf = (unsigned short*)ws;
    size_t need = (size_t)(ws - (char*)d_ws) + (size_t)B_ * C_ * N_ * T_ * 2;
    const bool use_bf = (ws_size >= need);

    {
        int pairs = B_ * N_ * (T_ / 4);  // 353,792 = 2764 * 128
        int blks = pairs / 128;
        if (use_bf)
            k_reduce<1><<<blks, 256, 0, stream>>>(x, alpha, Kt, xbf);
        else
            k_reduce<0><<<blks, 256, 0, stream>>>(x, alpha, Kt, xbf);
    }
    k_proj<<<B_ * (T_ / 32), 256, 0, stream>>>(Kt, W1, W2, KW1, QW2);
    k_softmax<<<B_ * T_, 64, 0, stream>>>(KW1, QW2, Apk);
    {
        dim3 grid(M_ / 32, B_);  // 614 x 16
        if (use_bf)
            k_out<1><<<grid, 384, 0, stream>>>(nullptr, xbf, Apk, out);
        else
            k_out<0><<<grid, 384, 0, stream>>>(x, nullptr, Apk, out);
    }
}